// Round 6
// baseline (416.256 us; speedup 1.0000x reference)
//
#include <hip/hip_runtime.h>
#include <hip/hip_bf16.h>

typedef __hip_bfloat16 bf16;
typedef __attribute__((ext_vector_type(8))) short short8;
typedef __attribute__((ext_vector_type(4))) float floatx4;

#define NC 4
#define BB 2
#define TS 16
#define CHN 3
#define HH 256
#define WW 256
#define KQ 256
#define EE 256
#define BKT 512          // B*K
#define HW 65536         // H*W
#define NSEG 25
#define CH1 32
#define CH1P 40
#define CH2 64
#define CH2P 72
#define PW 11            // plane width (11 cols)

// prep_kernel segment boundaries. Pipelined path launches only [0,P_LPW);
// fallback launches the full [0,P_ENDF) (m1w + aux conversions included).
#define P_WCL   32       // [0,32)      small tensors -> fp32 pool
#define P_W23   160      // [32,160)    conv2/3 weights -> channel-last bf16
#define P_LINV  224      // [160,224)   linv -> bf16 (padded K=1024)
#define P_PROJ  232      // [224,232)   projection (8 blocks)
#define P_CUBE  744      // [232,744)   cube sampling + fused v2v conv3d (512)
#define P_LPW   748      // [744,748)   lin_pos_w/lin_depth_w transpose
#define P_M1WE  1260     // [748,1260)  m1w -> bf16 permuted (fallback only)
#define P_ENDF  1452     // [1260,1452) f1w/f2w/m2w -> bf16 (fallback only)

__device__ __forceinline__ float tof(bf16 x){ return __bfloat162float(x); }
__device__ __forceinline__ bf16 tobf(float x){ return __float2bfloat16(x); }
// erf via Abramowitz-Stegun 7.1.26 (|eps| <= 1.5e-7, branch-free, native exp)
__device__ __forceinline__ float gelu_f(float x){
    float t = fabsf(x) * 0.70710678118654752f;
    float k = __builtin_amdgcn_rcpf(fmaf(0.3275911f, t, 1.f));
    float p = fmaf(fmaf(fmaf(fmaf(1.061405429f, k, -1.453152027f), k,
                   1.421413741f), k, -0.284496736f), k, 0.254829592f) * k;
    float e = __expf(-t*t);
    float er = fmaf(-p, e, 1.f);
    float s = copysignf(er, x);
    return 0.5f*x*(1.f + s);
}
__device__ __forceinline__ float ldx(const void* p, size_t i, int bf){
    return bf ? tof(((const bf16*)p)[i]) : ((const float*)p)[i];
}
__device__ __forceinline__ void gload_lds16(const void* g, void* l){
    __builtin_amdgcn_global_load_lds((const __attribute__((address_space(1))) void*)g,
                                     (__attribute__((address_space(3))) void*)l, 16, 0, 0);
}
__device__ __forceinline__ unsigned pack2(float a, float b){
    union{ bf16 h[2]; unsigned u; } pk; pk.h[0]=tobf(a); pk.h[1]=tobf(b); return pk.u;
}

struct CvtArgs { const void* src[NSEG]; int dstoff[NSEG]; int cnt[NSEG]; };

struct PrepArgs {
    const void *camF, *camR, *camC, *camP, *qc, *csc;
    const void *c2w, *c3w, *linv, *f1w, *f2w, *m2w, *m1w, *views;
    const void *v2vw, *v2vb;
    const void *linpw, *lindw;
    const int* qtime;
    bf16 *w2cl, *w3cl, *linv_bf, *f1w_bf, *f2w_bf, *m2w_bf, *m1w_bf;
    float *p2d, *visf;
    float *linpwT, *lindwT;
    bf16* volf;
    void* dout;
    int* flagp;
};

union PrepSm {
    struct { float vol[3][7][7][7]; float ws[648]; float bs[8]; } cube;  // 6,740 B
    bf16 lin[10368];                                                     // 20,736 B
};

// ---- movable bodies (called from prep in fallback, from launch A in pipeline)
__device__ __forceinline__ void m1w_body(bf16* lin, int n, int tid,
                                         const PrepArgs& a, int bf){
    // m1w row n -> bf16 with K-permutation [oc*81+pos] -> [pos*128+oc]
    const size_t off = (size_t)n*10368;
    if (bf){
        const bf16* s = (const bf16*)a.m1w + off;
        for (int i=tid;i<10368;i+=256) lin[i]=s[i];
    } else {
        const float* s = (const float*)a.m1w + off;
        for (int i=tid;i<10368;i+=256) lin[i]=tobf(s[i]);
    }
    __syncthreads();
    unsigned* d = (unsigned*)(a.m1w_bf + off);
    for (int j2=tid; j2<5184; j2+=256){
        int j = j2*2;
        int pos0=j>>7, oc0=j&127;
        int pos1=(j+1)>>7, oc1=(j+1)&127;
        d[j2] = pack2(tof(lin[oc0*81+pos0]), tof(lin[oc1*81+pos1]));
    }
}
__device__ __forceinline__ void aux3_body(int blk, int tid, const PrepArgs& a, int bf){
    int sub = blk>>6;
    int i0 = (blk&63)*256 + tid;
    const int stride = 64*256;
    if (sub==0){
        for (int i=i0; i<1024*256; i+=stride) a.f1w_bf[i]=tobf(ldx(a.f1w,i,bf));
    } else if (sub==1){
        for (int i=i0; i<256*1024; i+=stride) a.f2w_bf[i]=tobf(ldx(a.f2w,i,bf));
    } else {
        for (int i=i0; i<256*512; i+=stride) a.m2w_bf[i]=tobf(ldx(a.m2w,i,bf));
    }
}

// ---------------------------------------------------------------- fused prep
__global__ __launch_bounds__(256) void prep_kernel(CvtArgs ca, float* __restrict__ pool, PrepArgs a)
{
    int bid = blockIdx.x, tid = threadIdx.x;
    int bf = (((const unsigned short*)a.camF)[0] != 0) ? 1 : 0;
    __shared__ PrepSm sm;

    if (bid < P_WCL){
        for (int s=0; s<NSEG; ++s){
            const void* src = ca.src[s];
            float* d = pool + ca.dstoff[s];
            int n = ca.cnt[s];
            for (int i = bid*256 + tid; i < n; i += P_WCL*256) d[i] = ldx(src, i, bf);
        }
    } else if (bid < P_W23){
        int i0 = (bid-P_WCL)*256 + tid;
        const int stride = (P_W23-P_WCL)*256;
        for (int i=i0; i<64*32*9; i+=stride){
            int oc=i/(32*9), r=i%(32*9), ic=r/9, tap=r%9;
            a.w2cl[tap*(64*CH1) + oc*CH1 + ic] = tobf(ldx(a.c2w, i, bf));
        }
        for (int i=i0; i<128*64*9; i+=stride){
            int oc=i/(64*9), r=i%(64*9), ic=r/9, tap=r%9;
            a.w3cl[tap*(128*CH2) + oc*CH2 + ic] = tobf(ldx(a.c3w, i, bf));
        }
    } else if (bid < P_LINV){
        int i0 = (bid-P_W23)*256 + tid;
        const int stride = 64*256;
        for (int i=i0; i<256*1024; i+=stride){
            int r=i>>10, c=i&1023;
            a.linv_bf[i] = tobf(c<1000 ? ldx(a.linv, (size_t)r*1000+c, bf) : 0.f);
        }
    } else if (bid < P_PROJ){
        if (bid==P_LINV && tid==0) *a.flagp = bf;
        int idx = (bid-P_LINV)*256 + tid;
        if (idx < NC*BKT){
            int c = idx / BKT, bk = idx % BKT;
            float dx = ldx(a.qc,bk*3+0,bf) - ldx(a.camC,c*3+0,bf);
            float dy = ldx(a.qc,bk*3+1,bf) - ldx(a.camC,c*3+1,bf);
            float dz = ldx(a.qc,bk*3+2,bf) - ldx(a.camC,c*3+2,bf);
            float X0 = ldx(a.camR,c*9+0,bf)*dx + ldx(a.camR,c*9+1,bf)*dy + ldx(a.camR,c*9+2,bf)*dz;
            float X1 = ldx(a.camR,c*9+3,bf)*dx + ldx(a.camR,c*9+4,bf)*dy + ldx(a.camR,c*9+5,bf)*dz;
            float X2 = ldx(a.camR,c*9+6,bf)*dx + ldx(a.camR,c*9+7,bf)*dy + ldx(a.camR,c*9+8,bf)*dz;
            float z = fmaxf(X2, 1e-6f);
            float u = X0/z*ldx(a.camF,c*2+0,bf) + ldx(a.camP,c*2+0,bf);
            float v = X1/z*ldx(a.camF,c*2+1,bf) + ldx(a.camP,c*2+1,bf);
            a.p2d[idx*2+0] = u; a.p2d[idx*2+1] = v;
            bool vis = (X2 > 0.f) && (u >= 2.f) && (u <= (float)WW-2.f) && (v >= 2.f) && (v <= (float)HH-2.f);
            a.visf[idx] = vis ? 1.f : 0.f;
            float vv = vis ? 1.f : 0.f;
            size_t vidx = (size_t)BB*KQ*NC*EE + (size_t)bk*NC + c;
            if (bf) ((bf16*)a.dout)[vidx] = tobf(vv);
            else    ((float*)a.dout)[vidx] = vv;
        }
    } else if (bid < P_CUBE){
        // cube sampling ((p,cam)-parallel, 4-lane shuffle reduce) + fused v2v conv3d
        int bk = bid - P_PROJ;
        int c = tid & 3;
        int pg = tid >> 2;
        int b = bk >> 8;
        for (int i=tid; i<3*343; i+=256) ((float*)sm.cube.vol)[i]=0.f;
        for (int i=tid; i<648; i+=256) sm.cube.ws[i]=ldx(a.v2vw,i,bf);
        if (tid<8) sm.cube.bs[tid]=ldx(a.v2vb,tid,bf);
        __syncthreads();
        float cs2 = ldx(a.csc,0,bf) * 2.f;
        int t = a.qtime[bk];
        float qx0 = ldx(a.qc,bk*3+0,bf);
        float qy0 = ldx(a.qc,bk*3+1,bf);
        float qz0 = ldx(a.qc,bk*3+2,bf);
        float R0=ldx(a.camR,c*9+0,bf), R1=ldx(a.camR,c*9+1,bf), R2=ldx(a.camR,c*9+2,bf);
        float R3=ldx(a.camR,c*9+3,bf), R4=ldx(a.camR,c*9+4,bf), R5=ldx(a.camR,c*9+5,bf);
        float R6=ldx(a.camR,c*9+6,bf), R7=ldx(a.camR,c*9+7,bf), R8=ldx(a.camR,c*9+8,bf);
        float Cx=ldx(a.camC,c*3+0,bf), Cy=ldx(a.camC,c*3+1,bf), Cz=ldx(a.camC,c*3+2,bf);
        float Fx=ldx(a.camF,c*2+0,bf), Fy=ldx(a.camF,c*2+1,bf);
        float Px=ldx(a.camP,c*2+0,bf), Py=ldx(a.camP,c*2+1,bf);
        #pragma unroll
        for (int pass=0; pass<2; ++pass){
            int p = (pass<<6) + pg;
            bool act = p < 125;
            int i=p/25, j=(p/5)%5, kz=p%5;
            float a0=0.f,a1=0.f,a2=0.f,ms=0.f;
            if (act){
                float qx = qx0 + (float)(i-2)*cs2;
                float qy = qy0 + (float)(j-2)*cs2;
                float qz = qz0 + (float)(kz-2)*cs2;
                float dx=qx-Cx, dy=qy-Cy, dz=qz-Cz;
                float X0=R0*dx+R1*dy+R2*dz;
                float X1=R3*dx+R4*dy+R5*dz;
                float X2=R6*dx+R7*dy+R8*dz;
                float z = fmaxf(X2,1e-6f);
                float u = X0/z*Fx+Px, v = X1/z*Fy+Py;
                if (u>=0.f && u<=(float)WW && v>=0.f && v<=(float)HH){
                    ms = 1.f;
                    float x = u-0.5f, y = v-0.5f;
                    float xf = floorf(x), yf = floorf(y);
                    int ix=(int)xf, iy=(int)yf;
                    float wx=x-xf, wy=y-yf;
                    size_t basev = (size_t)((c*BB+b)*TS + t)*CHN*HW;
                    float wxs[2]={1.f-wx,wx}, wys[2]={1.f-wy,wy};
                    #pragma unroll
                    for (int ty=0;ty<2;++ty){
                        int yy=iy+ty; if (yy<0||yy>=HH) continue;
                        #pragma unroll
                        for (int tx=0;tx<2;++tx){
                            int xx=ix+tx; if (xx<0||xx>=WW) continue;
                            float wt=wys[ty]*wxs[tx];
                            size_t o = basev + (size_t)yy*WW+xx;
                            a0 += wt*ldx(a.views,o,bf);
                            a1 += wt*ldx(a.views,o+HW,bf);
                            a2 += wt*ldx(a.views,o+2*HW,bf);
                        }
                    }
                }
            }
            a0 += __shfl_xor(a0,1); a0 += __shfl_xor(a0,2);
            a1 += __shfl_xor(a1,1); a1 += __shfl_xor(a1,2);
            a2 += __shfl_xor(a2,1); a2 += __shfl_xor(a2,2);
            ms += __shfl_xor(ms,1); ms += __shfl_xor(ms,2);
            if (act && c==0){
                float cnt = fmaxf(ms,1.f);
                sm.cube.vol[0][kz+1][j+1][i+1]=a0/cnt;
                sm.cube.vol[1][kz+1][j+1][i+1]=a1/cnt;
                sm.cube.vol[2][kz+1][j+1][i+1]=a2/cnt;
            }
        }
        __syncthreads();
        if (tid >= 104 && tid < 128) a.volf[bk*1024 + 1000 + (tid-104)] = tobf(0.f);
        if (tid < 125){
            int w2=tid/25, h2=(tid/5)%5, d2=tid%5;
            for (int oc=0;oc<8;++oc){
                float acc = sm.cube.bs[oc];
                #pragma unroll
                for (int ic=0;ic<3;++ic)
                  #pragma unroll
                  for (int dz=0;dz<3;++dz)
                    #pragma unroll
                    for (int dy=0;dy<3;++dy)
                      #pragma unroll
                      for (int dxx=0;dxx<3;++dxx)
                        acc += sm.cube.vol[ic][d2+dz][h2+dy][w2+dxx] * sm.cube.ws[(((oc*3+ic)*3+dz)*3+dy)*3+dxx];
                a.volf[bk*1024 + oc*125 + tid] = tobf(gelu_f(acc));
            }
        }
    } else if (bid < P_LPW){
        // lin_pos_w [256][40] -> [40][256], lin_depth_w [256][20] -> [20][256]
        int i0 = (bid-P_CUBE)*256 + tid;         // 0..1023
        for (int o=i0; o<10240; o+=1024){
            int j=o>>8, e=o&255;
            a.linpwT[o] = ldx(a.linpw, (size_t)e*40+j, bf);
        }
        for (int o=i0; o<5120; o+=1024){
            int j=o>>8, e=o&255;
            a.lindwT[o] = ldx(a.lindw, (size_t)e*20+j, bf);
        }
    } else if (bid < P_M1WE){
        m1w_body(sm.lin, bid-P_LPW, tid, a, bf);
    } else {
        aux3_body(bid-P_M1WE, tid, a, bf);
    }
}

// ---------------------------------------------------------------- shared-mem layouts
struct __align__(16) PCShared {
    bf16 a2cl[11*PW*CH2P];   // 17,424 B
    bf16 a1cl[11*PW*CH1P];   // 9,680 B
    float w1s[864];          // 3,456 B
    float patch[3][11][11];  // 1,452 B
};
struct __align__(16) LVShared {
    bf16 As[64][72];
    bf16 Bs[64][72];         // 18,432 B total
};
struct __align__(16) G128Shared {
    bf16 As[128][64];
    bf16 Bs[128][64];        // 32,768 B total
};

// fused patch sample + conv1 (VALU) + conv2/conv3 (MFMA, swapped operands:
// mfma(W,Act) -> D[oc][pos], lane holds 4 consecutive oc -> 8B packed writes).
// act_out layout: [img][pos*128+oc] (m1w permuted to match).
__device__ __forceinline__ void patchconv_body(
    PCShared& sm, int img,
    const void* __restrict__ views, const float* __restrict__ p2d,
    const int* __restrict__ qtime,
    const float* __restrict__ w1, const float* __restrict__ b1,
    const bf16* __restrict__ w2cl, const float* __restrict__ b2,
    const bf16* __restrict__ w3cl, const float* __restrict__ b3,
    bf16* __restrict__ act_out, const int* __restrict__ flagp)
{
    int c = img>>9, b = (img>>8)&1, k = img&255;
    int bk = b*KQ + k;
    int tid = threadIdx.x;
    int wave = tid>>6, lane = tid&63;

    for (int i=tid;i<3*11*11;i+=256) ((float*)sm.patch)[i]=0.f;
    for (int i=tid;i<864;i+=256) sm.w1s[i]=w1[i];
    {
        unsigned int* z1=(unsigned int*)sm.a1cl; int n1 = 11*PW*CH1P/2;
        for (int i=tid;i<n1;i+=256) z1[i]=0u;
        unsigned int* z2=(unsigned int*)sm.a2cl; int n2 = 11*PW*CH2P/2;
        for (int i=tid;i<n2;i+=256) z2[i]=0u;
    }
    __syncthreads();
    if (tid<243){
        int bf = *flagp;
        int ch = tid/81;
        int pp = tid - ch*81;
        float u=p2d[(c*BKT+bk)*2+0], v=p2d[(c*BKT+bk)*2+1];
        int t=qtime[bk];
        int r=pp/9,q=pp%9;
        float x=u+(float)(q-4), y=v+(float)(r-4);
        float xf=floorf(x), yf=floorf(y);
        int ix=(int)xf, iy=(int)yf;
        float wx=x-xf, wy=y-yf;
        size_t base = (size_t)((c*BB+b)*TS+t)*CHN*HW + (size_t)ch*HW;
        float acc=0.f;
        float wxs[2]={1.f-wx,wx}, wys[2]={1.f-wy,wy};
        #pragma unroll
        for (int ty=0;ty<2;++ty){
            int yy=iy+ty; if (yy<0||yy>=HH) continue;
            #pragma unroll
            for (int tx=0;tx<2;++tx){
                int xx=ix+tx; if (xx<0||xx>=WW) continue;
                acc += wys[ty]*wxs[tx]*ldx(views, base + (size_t)yy*WW+xx, bf);
            }
        }
        sm.patch[ch][r+1][q+1]=acc;
    }
    __syncthreads();
    for (int o=tid;o<81*32;o+=256){
        int oc=o&31, pp=o>>5;
        int r=pp/9, q=pp-9*r;
        float acc=b1[oc];
        #pragma unroll
        for (int ic=0;ic<3;++ic)
          #pragma unroll
          for (int dy2=0;dy2<3;++dy2)
            #pragma unroll
            for (int dx2=0;dx2<3;++dx2)
              acc += sm.patch[ic][r+dy2][q+dx2]*sm.w1s[((oc*3+ic)*3+dy2)*3+dx2];
        sm.a1cl[((r+1)*PW+(q+1))*CH1P + oc] = tobf(gelu_f(acc));
    }
    __syncthreads();
    int mrow = lane&15;
    int kgrp = lane>>4;
    int koff = kgrp<<3;
    // ---- conv2: D[oc][pos]
    {
        int baseoff[6];
        #pragma unroll
        for (int m=0;m<6;++m){
            int pos = m*16 + mrow; if (pos>80) pos=80;
            int r=pos/9, q=pos-9*r;
            baseoff[m] = (r*PW+q)*CH1P + koff;
        }
        floatx4 acc2[6];
        #pragma unroll
        for (int m=0;m<6;++m) acc2[m]=(floatx4){0.f,0.f,0.f,0.f};
        int n0 = wave<<4;
        #pragma unroll
        for (int tap=0; tap<9; ++tap){
            int dy=tap/3, dx=tap-3*dy;
            short8 wfrag = *(const short8*)(w2cl + ((size_t)tap*64 + n0 + mrow)*CH1 + koff);
            int toff = (dy*PW+dx)*CH1P;
            #pragma unroll
            for (int m=0;m<6;++m){
                short8 afrag = *(const short8*)&sm.a1cl[baseoff[m]+toff];
                acc2[m] = __builtin_amdgcn_mfma_f32_16x16x32_bf16(wfrag, afrag, acc2[m], 0,0,0);
            }
        }
        int ocb = n0 + (kgrp<<2);
        float bb0=b2[ocb], bb1=b2[ocb+1], bb2=b2[ocb+2], bb3=b2[ocb+3];
        #pragma unroll
        for (int m=0;m<6;++m){
            int pos = m*16 + mrow;
            if (pos<=80){
                int r=pos/9,q=pos-9*r;
                uint2 pk;
                pk.x = pack2(gelu_f(acc2[m][0]+bb0), gelu_f(acc2[m][1]+bb1));
                pk.y = pack2(gelu_f(acc2[m][2]+bb2), gelu_f(acc2[m][3]+bb3));
                *(uint2*)&sm.a2cl[((r+1)*PW+(q+1))*CH2P + ocb] = pk;
            }
        }
    }
    __syncthreads();
    // ---- conv3: D[oc][pos]
    {
        int baseoff[6];
        #pragma unroll
        for (int m=0;m<6;++m){
            int pos = m*16 + mrow; if (pos>80) pos=80;
            int r=pos/9, q=pos-9*r;
            baseoff[m] = (r*PW+q)*CH2P;
        }
        floatx4 acc3[2][6];
        #pragma unroll
        for (int nt=0;nt<2;++nt)
          #pragma unroll
          for (int m=0;m<6;++m) acc3[nt][m]=(floatx4){0.f,0.f,0.f,0.f};
        int n0 = wave<<5;
        #pragma unroll
        for (int tap=0; tap<9; ++tap){
            int dy=tap/3, dx=tap-3*dy;
            int toff = (dy*PW+dx)*CH2P;
            #pragma unroll
            for (int ks=0;ks<2;++ks){
                int kof2 = (ks<<5) + koff;
                short8 w0 = *(const short8*)(w3cl + ((size_t)tap*128 + n0      + mrow)*CH2 + kof2);
                short8 w1f= *(const short8*)(w3cl + ((size_t)tap*128 + n0 + 16 + mrow)*CH2 + kof2);
                #pragma unroll
                for (int m=0;m<6;++m){
                    short8 af = *(const short8*)&sm.a2cl[baseoff[m]+toff+kof2];
                    acc3[0][m] = __builtin_amdgcn_mfma_f32_16x16x32_bf16(w0,  af, acc3[0][m], 0,0,0);
                    acc3[1][m] = __builtin_amdgcn_mfma_f32_16x16x32_bf16(w1f, af, acc3[1][m], 0,0,0);
                }
            }
        }
        bf16* outp = act_out + (size_t)img*10368;
        #pragma unroll
        for (int nt=0;nt<2;++nt){
            int ocb = n0 + (nt<<4) + (kgrp<<2);
            float bb0=b3[ocb], bb1=b3[ocb+1], bb2=b3[ocb+2], bb3=b3[ocb+3];
            #pragma unroll
            for (int m=0;m<6;++m){
                int pos = m*16 + mrow;
                if (pos<=80){
                    uint2 pk;
                    pk.x = pack2(gelu_f(acc3[nt][m][0]+bb0), gelu_f(acc3[nt][m][1]+bb1));
                    pk.y = pack2(gelu_f(acc3[nt][m][2]+bb2), gelu_f(acc3[nt][m][3]+bb3));
                    *(uint2*)&outp[pos*128 + ocb] = pk;
                }
            }
        }
    }
}

// linvol 64x64 GEMM body (single-buffered), split-K z-slice -> private partials
__device__ __forceinline__ void linvol_body(
    LVShared& sm, int r, const bf16* __restrict__ A, const bf16* __restrict__ W,
    float* __restrict__ lvparts)
{
    int tid = threadIdx.x;
    int wave = tid>>6, lane = tid&63;
    int z = r>>5, rem = r&31, by = rem>>2, bx = rem&3;
    int m0 = by<<6, n0 = bx<<6;
    int kt0 = z*2;
    int lr = tid>>3, lc = (tid&7)<<3;
    floatx4 acc[4];
    #pragma unroll
    for (int j=0;j<4;++j) acc[j]=(floatx4){0.f,0.f,0.f,0.f};
    int arow = (wave<<4) + (lane&15);
    int koff = (lane>>4)<<3;
    int nrow = lane&15;
    for (int it=0; it<2; ++it){
        int ko = (kt0+it)<<6;
        *(uint4*)&sm.As[lr][lc]    = *(const uint4*)(A + (size_t)(m0+lr)*1024    + ko + lc);
        *(uint4*)&sm.As[lr+32][lc] = *(const uint4*)(A + (size_t)(m0+lr+32)*1024 + ko + lc);
        *(uint4*)&sm.Bs[lr][lc]    = *(const uint4*)(W + (size_t)(n0+lr)*1024    + ko + lc);
        *(uint4*)&sm.Bs[lr+32][lc] = *(const uint4*)(W + (size_t)(n0+lr+32)*1024 + ko + lc);
        __syncthreads();
        #pragma unroll
        for (int kk=0; kk<64; kk+=32){
            short8 af = *(const short8*)&sm.As[arow][kk+koff];
            #pragma unroll
            for (int j=0;j<4;++j){
                short8 wf = *(const short8*)&sm.Bs[(j<<4)+nrow][kk+koff];
                acc[j] = __builtin_amdgcn_mfma_f32_16x16x32_bf16(af, wf, acc[j], 0,0,0);
            }
        }
        __syncthreads();
    }
    float* out = lvparts + (size_t)z * (512*256);
    int crow = (wave<<4) + ((lane>>4)<<2);
    int ccol = lane&15;
    #pragma unroll
    for (int j=0;j<4;++j){
        int n = n0 + (j<<4) + ccol;
        #pragma unroll
        for (int rr=0;rr<4;++rr)
            out[(size_t)(m0+crow+rr)*256 + n] = acc[j][rr];
    }
}

// m97-style 128x128-tile GEMM body for mlp1 chunks (M=1024, N=512, K=10368,
// split-K=8 -> private partials). bid3 flattens dim3(4,8,8).
__device__ __forceinline__ void gemm128_body(
    G128Shared& s, int bid3, const bf16* __restrict__ A, const bf16* __restrict__ W,
    float* __restrict__ Cf, int pstride)
{
    const int N=512, K=10368, kit=162, zdiv=8;
    int tid = threadIdx.x;
    int wave = tid>>6, lane = tid&63;
    int m0 = ((bid3>>2)&7)<<7, n0 = (bid3&3)<<7;
    int bz = bid3>>5;
    int it0 = (int)(((long)bz     * kit) / zdiv);
    int it1 = (int)(((long)(bz+1) * kit) / zdiv);
    float* out = Cf + (size_t)bz * pstride;
    int srow = (wave<<5) + (lane>>3);
    int scol = (lane&7)<<3;
    const bf16* Ap = A + (size_t)(m0+srow)*K + ((size_t)it0<<6) + scol;
    const bf16* Bp = W + (size_t)(n0+srow)*K + ((size_t)it0<<6) + scol;
    bf16* AsW = &s.As[wave<<5][0];
    bf16* BsW = &s.Bs[wave<<5][0];
    floatx4 acc[4][4];
    #pragma unroll
    for (int i=0;i<4;++i)
      #pragma unroll
      for (int j=0;j<4;++j) acc[i][j] = (floatx4){0.f,0.f,0.f,0.f};
    int wm = (wave>>1)<<6, wn = (wave&1)<<6;
    int frow = lane&15, koff = (lane>>4)<<3;
    for (int it=it0; it<it1; ++it){
        size_t off = (size_t)(it-it0)<<6;
        #pragma unroll
        for (int j=0;j<4;++j){
            gload_lds16(Ap + (size_t)(j<<3)*K + off, AsW + (j<<3)*64);
            gload_lds16(Bp + (size_t)(j<<3)*K + off, BsW + (j<<3)*64);
        }
        __syncthreads();
        #pragma unroll
        for (int kk=0;kk<64;kk+=32){
            short8 af[4], bfv[4];
            #pragma unroll
            for (int i=0;i<4;++i) af[i]  = *(const short8*)&s.As[wm + (i<<4) + frow][kk+koff];
            #pragma unroll
            for (int j=0;j<4;++j) bfv[j] = *(const short8*)&s.Bs[wn + (j<<4) + frow][kk+koff];
            #pragma unroll
            for (int i=0;i<4;++i)
              #pragma unroll
              for (int j=0;j<4;++j)
                acc[i][j] = __builtin_amdgcn_mfma_f32_16x16x32_bf16(af[i], bfv[j], acc[i][j], 0,0,0);
        }
        __syncthreads();
    }
    int crow = (lane>>4)<<2;
    int ccol = lane&15;
    #pragma unroll
    for (int i=0;i<4;++i){
        int mrow = m0 + wm + (i<<4) + crow;
        #pragma unroll
        for (int j=0;j<4;++j){
            int n = n0 + wn + (j<<4) + ccol;
            #pragma unroll
            for (int r=0;r<4;++r)
                out[(size_t)(mrow+r)*N + n] = acc[i][j][r];
        }
    }
}

// ---------------------------------------------------------------- launch A:
// PC chunk0 [0,1024) | linvol [1024,1280) | m1w-permute [1280,1792) | aux [1792,1984)
__global__ __launch_bounds__(256) void patchlinA_kernel(
    PrepArgs a, const float* __restrict__ w1, const float* __restrict__ b1,
    const float* __restrict__ b2, const float* __restrict__ b3,
    bf16* __restrict__ act_out, float* __restrict__ lvparts)
{
    __shared__ union { PCShared pc; LVShared lv; bf16 lin[10368]; } sm;
    int bid = blockIdx.x, tid = threadIdx.x;
    if (bid < 1024){
        patchconv_body(sm.pc, bid, a.views, a.p2d, a.qtime, w1, b1, a.w2cl, b2, a.w3cl, b3,
                       act_out, a.flagp);
    } else if (bid < 1280){
        linvol_body(sm.lv, bid-1024, a.volf, a.linv_bf, lvparts);
    } else if (bid < 1792){
        int bf = (((const unsigned short*)a.camF)[0] != 0) ? 1 : 0;
        m1w_body(sm.lin, bid-1280, tid, a, bf);
    } else {
        int bf = (((const unsigned short*)a.camF)[0] != 0) ? 1 : 0;
        aux3_body(bid-1792, tid, a, bf);
    }
}

// ---------------------------------------------------------------- launch B:
// gemm128 chunk0 [0,256) | PC chunk1 [256,1280)
__global__ __launch_bounds__(256) void pc_g128_kernel(
    const void* __restrict__ views, const float* __restrict__ p2d,
    const int* __restrict__ qtime,
    const float* __restrict__ w1, const float* __restrict__ b1,
    const bf16* __restrict__ w2cl, const float* __restrict__ b2,
    const bf16* __restrict__ w3cl, const float* __restrict__ b3,
    bf16* __restrict__ act_out, const int* __restrict__ flagp,
    const bf16* __restrict__ m1w_bf, float* __restrict__ partsA)
{
    __shared__ union { PCShared pc; G128Shared g; } sm;
    int bid = blockIdx.x;
    if (bid < 256){
        gemm128_body(sm.g, bid, act_out, m1w_bf, partsA, 1024*512);
    } else {
        patchconv_body(sm.pc, 1024 + (bid-256), views, p2d, qtime, w1, b1, w2cl, b2, w3cl, b3,
                       act_out, flagp);
    }
}

// ---------------------------------------------------------------- launch C:
// gemm128 chunk1 [0,256) | mlp1_fin chunk0 [256,512)
__global__ __launch_bounds__(256) void g128_fin_kernel(
    const bf16* __restrict__ A1, const bf16* __restrict__ m1w_bf,
    float* __restrict__ partsB, const float* __restrict__ partsA,
    const float* __restrict__ m1b, bf16* __restrict__ out0)
{
    __shared__ G128Shared g;
    int bid = blockIdx.x, tid = threadIdx.x;
    if (bid < 256){
        gemm128_body(g, bid, A1, m1w_bf, partsB, 1024*512);
    } else {
        for (int i=(bid-256)*256+tid; i<1024*512; i+=256*256){
            float s = m1b[i & 511];
            #pragma unroll
            for (int p=0;p<8;++p) s += partsA[(size_t)p*(1024*512) + i];
            out0[i] = tobf(gelu_f(s));
        }
    }
}

// ---------------------------------------------------------------- fallback standalone kernels
__global__ __launch_bounds__(256) void patchconv_kernel(
    const void* __restrict__ views, const float* __restrict__ p2d,
    const int* __restrict__ qtime,
    const float* __restrict__ w1, const float* __restrict__ b1,
    const bf16* __restrict__ w2cl, const float* __restrict__ b2,
    const bf16* __restrict__ w3cl, const float* __restrict__ b3,
    bf16* __restrict__ act_out, int img0, const int* __restrict__ flagp)
{
    __shared__ PCShared sm;
    patchconv_body(sm, img0+blockIdx.x, views, p2d, qtime, w1, b1, w2cl, b2, w3cl, b3,
                   act_out, flagp);
}

__global__ __launch_bounds__(256) void gemm128_kernel(
    const bf16* __restrict__ A, const bf16* __restrict__ W,
    float* __restrict__ Cf, int N, int K, int kiters_total, int zdiv, int pstride)
{
    __shared__ G128Shared s;
    int tid = threadIdx.x;
    int wave = tid>>6, lane = tid&63;
    int m0 = blockIdx.y<<7, n0 = blockIdx.x<<7;
    int it0 = (int)(((long)blockIdx.z     * kiters_total) / zdiv);
    int it1 = (int)(((long)(blockIdx.z+1) * kiters_total) / zdiv);
    float* out = Cf + (size_t)blockIdx.z * pstride;
    int srow = (wave<<5) + (lane>>3);
    int scol = (lane&7)<<3;
    const bf16* Ap = A + (size_t)(m0+srow)*K + ((size_t)it0<<6) + scol;
    const bf16* Bp = W + (size_t)(n0+srow)*K + ((size_t)it0<<6) + scol;
    bf16* AsW = &s.As[wave<<5][0];
    bf16* BsW = &s.Bs[wave<<5][0];
    floatx4 acc[4][4];
    #pragma unroll
    for (int i=0;i<4;++i)
      #pragma unroll
      for (int j=0;j<4;++j) acc[i][j] = (floatx4){0.f,0.f,0.f,0.f};
    int wm = (wave>>1)<<6, wn = (wave&1)<<6;
    int frow = lane&15, koff = (lane>>4)<<3;
    for (int it=it0; it<it1; ++it){
        size_t off = (size_t)(it-it0)<<6;
        #pragma unroll
        for (int j=0;j<4;++j){
            gload_lds16(Ap + (size_t)(j<<3)*K + off, AsW + (j<<3)*64);
            gload_lds16(Bp + (size_t)(j<<3)*K + off, BsW + (j<<3)*64);
        }
        __syncthreads();
        #pragma unroll
        for (int kk=0;kk<64;kk+=32){
            short8 af[4], bfv[4];
            #pragma unroll
            for (int i=0;i<4;++i) af[i]  = *(const short8*)&s.As[wm + (i<<4) + frow][kk+koff];
            #pragma unroll
            for (int j=0;j<4;++j) bfv[j] = *(const short8*)&s.Bs[wn + (j<<4) + frow][kk+koff];
            #pragma unroll
            for (int i=0;i<4;++i)
              #pragma unroll
              for (int j=0;j<4;++j)
                acc[i][j] = __builtin_amdgcn_mfma_f32_16x16x32_bf16(af[i], bfv[j], acc[i][j], 0,0,0);
        }
        __syncthreads();
    }
    int crow = (lane>>4)<<2;
    int ccol = lane&15;
    #pragma unroll
    for (int i=0;i<4;++i){
        int mrow = m0 + wm + (i<<4) + crow;
        #pragma unroll
        for (int j=0;j<4;++j){
            int n = n0 + wn + (j<<4) + ccol;
            #pragma unroll
            for (int r=0;r<4;++r)
                out[(size_t)(mrow+r)*N + n] = acc[i][j][r];
        }
    }
}

// ---------------------------------------------------------------- generic MFMA bf16 GEMM (small GEMMs)
// OUT=1: bf16 = gelu(acc+bias); OUT=2: fp32 store (z-slice -> Cf + z*pstride)
template<int OUT>
__global__ __launch_bounds__(256) void gemm_bf16_kernel(
    const bf16* __restrict__ A, const bf16* __restrict__ W, const float* __restrict__ bias,
    float* __restrict__ Cf, void* __restrict__ Cb, int M, int N, int K, int iters,
    int pstride)
{
    __shared__ bf16 As[2][64][72];
    __shared__ bf16 Bs[2][64][72];
    int tid = threadIdx.x;
    int wave = tid>>6, lane = tid&63;
    int m0 = blockIdx.y<<6, n0 = blockIdx.x<<6;
    int kt0 = blockIdx.z*iters;
    int lr = tid>>3;
    int lc = (tid&7)<<3;
    const bf16* Ap0 = A + (size_t)(m0+lr)*K    + (kt0<<6) + lc;
    const bf16* Ap1 = A + (size_t)(m0+lr+32)*K + (kt0<<6) + lc;
    const bf16* Wp0 = W + (size_t)(n0+lr)*K    + (kt0<<6) + lc;
    const bf16* Wp1 = W + (size_t)(n0+lr+32)*K + (kt0<<6) + lc;
    uint4 ra0 = *(const uint4*)Ap0;
    uint4 ra1 = *(const uint4*)Ap1;
    uint4 rb0 = *(const uint4*)Wp0;
    uint4 rb1 = *(const uint4*)Wp1;
    floatx4 acc[4];
    #pragma unroll
    for (int j=0;j<4;++j) acc[j] = (floatx4){0.f,0.f,0.f,0.f};
    int arow = (wave<<4) + (lane&15);
    int koff = (lane>>4)<<3;
    int nrow = lane&15;
    *(uint4*)&As[0][lr][lc]    = ra0;
    *(uint4*)&As[0][lr+32][lc] = ra1;
    *(uint4*)&Bs[0][lr][lc]    = rb0;
    *(uint4*)&Bs[0][lr+32][lc] = rb1;
    __syncthreads();
    for (int it=0; it<iters; ++it){
        int cur = it&1;
        if (it+1<iters){
            int off = (it+1)<<6;
            ra0 = *(const uint4*)(Ap0+off);
            ra1 = *(const uint4*)(Ap1+off);
            rb0 = *(const uint4*)(Wp0+off);
            rb1 = *(const uint4*)(Wp1+off);
        }
        #pragma unroll
        for (int kk=0; kk<64; kk+=32){
            short8 af = *(const short8*)&As[cur][arow][kk+koff];
            #pragma unroll
            for (int j=0;j<4;++j){
                short8 bfr = *(const short8*)&Bs[cur][(j<<4)+nrow][kk+koff];
                acc[j] = __builtin_amdgcn_mfma_f32_16x16x32_bf16(af, bfr, acc[j], 0, 0, 0);
            }
        }
        if (it+1<iters){
            __syncthreads();
            int nxt = cur^1;
            *(uint4*)&As[nxt][lr][lc]    = ra0;
            *(uint4*)&As[nxt][lr+32][lc] = ra1;
            *(uint4*)&Bs[nxt][lr][lc]    = rb0;
            *(uint4*)&Bs[nxt][lr+32][lc] = rb1;
            __syncthreads();
        }
    }
    int crow = (wave<<4) + ((lane>>4)<<2);
    int ccol = lane&15;
    #pragma unroll
    for (int j=0;j<4;++j){
        int n = n0 + (j<<4) + ccol;
        if (OUT==1){
            float bb = bias[n];
            #pragma unroll
            for (int r=0;r<4;++r)
                ((bf16*)Cb)[(size_t)(m0+crow+r)*N + n] = tobf(gelu_f(acc[j][r] + bb));
        } else {
            float* out = Cf + (size_t)blockIdx.z * pstride;
            #pragma unroll
            for (int r=0;r<4;++r)
                out[(size_t)(m0+crow+r)*N + n] = acc[j][r];
        }
    }
}

// ---------------------------------------------------------------- mlp1 finalize
__global__ __launch_bounds__(256) void mlp1_fin_kernel(const float* __restrict__ P,
                                                       const float* __restrict__ bias,
                                                       bf16* __restrict__ Cb, int total, int Nmask,
                                                       int pstride){
    for (int i = blockIdx.x*256 + threadIdx.x; i < total; i += gridDim.x*256){
        float s = bias[i & Nmask];
        #pragma unroll
        for (int p=0;p<8;++p) s += P[(size_t)p*pstride + i];
        Cb[i] = tobf(gelu_f(s));
    }
}

// ---------------------------------------------------------------- fus2 finalize
__global__ __launch_bounds__(256) void fin2_kernel(const float* __restrict__ P,
                                                   const float* __restrict__ bias,
                                                   void* __restrict__ out, const int* __restrict__ flagp,
                                                   int total, int mask, int pstride){
    int bf = *flagp;
    for (int i = blockIdx.x*256 + threadIdx.x; i < total; i += gridDim.x*256){
        float s = bias[i & mask];
        #pragma unroll
        for (int p=0;p<4;++p) s += P[(size_t)p*pstride + i];
        if (bf) ((bf16*)out)[i] = tobf(s);
        else    ((float*)out)[i] = s;
    }
}

// ---------------------------------------------------------------- terms + gates + fuse
__global__ __launch_bounds__(256) void terms_kernel(
    const float* __restrict__ p2d, const float* __restrict__ visf,
    const float* __restrict__ lvp, const float* __restrict__ linv_b,
    const float* __restrict__ m2p, const float* __restrict__ m2_b,
    const float* __restrict__ linpwT, const float* __restrict__ lin_pos_b,
    const float* __restrict__ lindwT, const float* __restrict__ lin_depth_b,
    const float* __restrict__ tq_emb, const float* __restrict__ tt_emb,
    const float* __restrict__ vis_tab,
    const float* __restrict__ gate_w, const float* __restrict__ gate_b,
    const int* __restrict__ qtime, const int* __restrict__ ttime,
    const float* __restrict__ qc, const float* __restrict__ camC,
    const float* __restrict__ csc, const float* __restrict__ dns,
    bf16* __restrict__ fused)
{
    int row = blockIdx.x;
    int c = row & 3; int bk = row >> 2;
    int tid = threadIdx.x;
    __shared__ float feats[40];
    __shared__ float dfeat[20];
    __shared__ float terms[7][256];
    __shared__ float wred[4][7];
    __shared__ float gates_s[7];
    float u = p2d[(c*BKT+bk)*2+0], v = p2d[(c*BKT+bk)*2+1];
    if (tid < 40){
        int j = tid/20; int rem = tid%20;
        float xval = (j==0) ? u*(1.f/(float)WW) : v*(1.f/(float)HH);
        int fi = rem % 10; bool iscos = (rem >= 10);
        float arg = xval * (float)(1<<fi) * 3.14159265358979323846f;
        feats[tid] = iscos ? cosf(arg) : sinf(arg);
    } else if (tid < 60){
        int rem = tid-40;
        float dx = qc[bk*3+0]-camC[c*3+0];
        float dy = qc[bk*3+1]-camC[c*3+1];
        float dz = qc[bk*3+2]-camC[c*3+2];
        float dep = sqrtf(dx*dx+dy*dy+dz*dz) / (csc[0] * dns[0]);
        int fi = rem % 10; bool iscos = (rem >= 10);
        float arg = dep * (float)(1<<fi) * 3.14159265358979323846f;
        dfeat[rem] = iscos ? cosf(arg) : sinf(arg);
    }
    __syncthreads();
    int e = tid;
    float pos = lin_pos_b[e];
    #pragma unroll
    for (int j2=0;j2<40;++j2) pos += feats[j2]*linpwT[j2*256+e];
    float dep = lin_depth_b[e];
    #pragma unroll
    for (int j2=0;j2<20;++j2) dep += dfeat[j2]*lindwT[j2*256+e];
    float vol = linv_b[e];
    #pragma unroll
    for (int p=0;p<8;++p) vol += lvp[(size_t)p*(512*256) + bk*256+e];
    int img = (c*BB + (bk>>8))*KQ + (bk&255);
    float pat = m2_b[e] + m2p[(size_t)img*256+e] + m2p[(size_t)(2048*256) + (size_t)img*256+e];
    int tq = qtime[bk], tt2 = ttime[bk];
    float qtv = tq_emb[tq*256+e];
    float ttv = tt_emb[tt2*256+e];
    int vb = (visf[c*BKT+bk] > 0.5f) ? 1 : 0;
    float viv = vis_tab[vb*256+e];
    terms[0][e]=pos; terms[1][e]=vol; terms[2][e]=pat; terms[3][e]=qtv;
    terms[4][e]=ttv; terms[5][e]=viv; terms[6][e]=dep;
    __syncthreads();
    float pg[7];
    #pragma unroll
    for (int g=0;g<7;++g) pg[g]=0.f;
    for (int j2=tid; j2<1792; j2+=256){
        float cv = ((const float*)terms)[j2];
        #pragma unroll
        for (int g=0;g<7;++g) pg[g] += cv * gate_w[g*1792 + j2];
    }
    #pragma unroll
    for (int g=0;g<7;++g){
        #pragma unroll
        for (int off=32; off>0; off>>=1) pg[g] += __shfl_down(pg[g], off, 64);
    }
    int wave = tid >> 6, lane = tid & 63;
    if (lane==0){
        #pragma unroll
        for (int g=0;g<7;++g) wred[wave][g]=pg[g];
    }
    __syncthreads();
    if (tid < 7){
        float s = wred[0][tid]+wred[1][tid]+wred[2][tid]+wred[3][tid] + gate_b[tid];
        gates_s[tid] = 1.f/(1.f+expf(-s));
    }
    __syncthreads();
    float fv = 0.f;
    #pragma unroll
    for (int g=0;g<7;++g) fv += gates_s[g]*terms[g][e];
    fused[(size_t)row*256 + e] = tobf(fv);
}

// ---------------------------------------------------------------- launch
extern "C" void kernel_launch(void* const* d_in, const int* in_sizes, int n_in,
                              void* d_out, int out_size, void* d_ws, size_t ws_size,
                              hipStream_t stream) {
    const void* views  = d_in[0];
    const int*  qtime  = (const int*)d_in[6];
    const int*  ttime  = (const int*)d_in[7];

    char* base = (char*)d_ws;
    int*   flag = (int*)base;                       // 256 B
    float* pool = (float*)(base + 256);

    CvtArgs ca; int poff = 0; int ns = 0;
    auto add = [&](const void* p, int n)->float* {
        ca.src[ns]=p; ca.dstoff[ns]=poff; ca.cnt[ns]=n;
        float* r = pool+poff; poff += n; ns++; return r;
    };
    float* P_camR = add(d_in[1],36);
    float* P_camC = add(d_in[2],12);
    float* P_camF = add(d_in[3],8);
    float* P_camP = add(d_in[4],8);
    float* P_qc   = add(d_in[5],1536);
    float* P_csc  = add(d_in[8],1);
    float* P_dns  = add(d_in[30],1);
    float* P_linvb= add(d_in[12],256);
    float* P_linpw= add(d_in[13],10240);
    float* P_linpb= add(d_in[14],256);
    float* P_lindw= add(d_in[15],5120);
    float* P_lindb= add(d_in[16],256);
    float* P_c1w  = add(d_in[17],864);
    float* P_c1b  = add(d_in[18],32);
    float* P_c2b  = add(d_in[20],64);
    float* P_c3b  = add(d_in[22],128);
    float* P_m1b  = add(d_in[24],512);
    float* P_m2b  = add(d_in[26],256);
    float* P_tq   = add(d_in[27],4096);
    float* P_tt   = add(d_in[28],4096);
    float* P_vtab = add(d_in[29],512);
    float* P_gw   = add(d_in[31],12544);
    float* P_gb   = add(d_in[32],7);
    float* P_f1b  = add(d_in[34],1024);
    float* P_f2b  = add(d_in[36],256);

    bf16* m1w_bf = (bf16*)(base + 4185600);          // 10,616,832 B
    bf16* w2cl   = (bf16*)(base + 14802432);         // 36,864 B
    bf16* w3cl   = (bf16*)(base + 14839296);         // 147,456 B
    bf16* linv_bf= (bf16*)(base + 14986752);         // 524,288 B
    bf16* f1w_bf = (bf16*)(base + 15511040);         // 524,288 B
    bf16* f2w_bf = (bf16*)(base + 16035328);         // 524,288 B
    bf16* m2w_bf = (bf16*)(base + 16559616);         // 262,144 B
    float* p2d   = (float*)(base + 16821760);        // 16,384 B
    float* visf  = (float*)(base + 16838144);        // 8,192 B
    bf16*  volf_bf = (bf16*)(base + 16846336);       // 1,048,576 B
    float* lvparts = (float*)(base + 17894912);      // 8 x 512x256 fp32 = 4,194,304 B
    float* linpwT  = (float*)(base + 22089216);      // 40,960 B
    float* lindwT  = (float*)(base + 22130176);      // 20,480 B
    bf16*  mlp1o_bf = (bf16*)(base + 24186368);      // 2,097,152 B
    bf16*  fusedb_bf= (bf16*)(base + 26283520);      // 1,048,576 B
    // transients (disjoint lifetimes): c3act [27.3M,69.8M) dead after gemm128;
    // hbuf/m2parts/f2parts live inside dead c3act range afterwards.
    bf16*  c3act    = (bf16*)(base + 27332096);      // 2048*10368*2 = 42,467,328 B
    bf16*  hbuf_bf  = (bf16*)(base + 27332096);      // 4 MB (fus1 output)
    float* m2parts  = (float*)(base + 31526400);     // 2 x 2048x256 fp32 = 4 MB
    float* f2parts  = (float*)(base + 35720704);     // 4 x 2048x256 fp32 = 8 MB
    float* partsA   = (float*)(base + 69799424);     // 8 x 1024x512 fp32 = 16 MB
    float* partsB   = (float*)(base + 86576640);     // 8 x 1024x512 fp32 = 16 MB -> ends 103,353,856

    PrepArgs pa;
    pa.camF=d_in[3]; pa.camR=d_in[1]; pa.camC=d_in[2]; pa.camP=d_in[4];
    pa.qc=d_in[5]; pa.csc=d_in[8];
    pa.c2w=d_in[19]; pa.c3w=d_in[21];
    pa.linv=d_in[11]; pa.f1w=d_in[33]; pa.f2w=d_in[35]; pa.m2w=d_in[25];
    pa.m1w=d_in[23]; pa.views=views;
    pa.v2vw=d_in[9]; pa.v2vb=d_in[10];
    pa.linpw=d_in[13]; pa.lindw=d_in[15];
    pa.qtime=qtime;
    pa.w2cl=w2cl; pa.w3cl=w3cl; pa.linv_bf=linv_bf; pa.f1w_bf=f1w_bf;
    pa.f2w_bf=f2w_bf; pa.m2w_bf=m2w_bf; pa.m1w_bf=m1w_bf;
    pa.p2d=p2d; pa.visf=visf; pa.volf=volf_bf;
    pa.linpwT=linpwT; pa.lindwT=lindwT;
    pa.dout=d_out; pa.flagp=flag;

    bool pipe = (ws_size >= 103353856ull);

    if (pipe){
        // prep: only what launch A needs (cvt/proj/cube/linv/transpose)
        prep_kernel<<<P_LPW, 256, 0, stream>>>(ca, pool, pa);
        // A: PC chunk0 + linvol + m1w-permute + f1/f2/m2 cvt (1984 blocks)
        patchlinA_kernel<<<1984, 256, 0, stream>>>(pa, P_c1w, P_c1b, P_c2b, P_c3b,
                                                   c3act, lvparts);
        // B: gemm128 chunk0 + PC chunk1 (1280 blocks)
        pc_g128_kernel<<<1280, 256, 0, stream>>>(views, p2d, qtime, P_c1w, P_c1b,
                                                 w2cl, P_c2b, w3cl, P_c3b, c3act, flag,
                                                 m1w_bf, partsA);
        // C: gemm128 chunk1 + mlp1_fin chunk0 (512 blocks)
        g128_fin_kernel<<<512, 256, 0, stream>>>(c3act + (size_t)1024*10368, m1w_bf,
                                                 partsB, partsA, P_m1b, mlp1o_bf);
        // D: mlp1_fin chunk1
        mlp1_fin_kernel<<<512, 256, 0, stream>>>(partsB, P_m1b, mlp1o_bf + (size_t)1024*512,
                                                 1024*512, 511, 1024*512);
    } else {
        // fallback: full prep + serial 2-chunk flow
        prep_kernel<<<P_ENDF, 256, 0, stream>>>(ca, pool, pa);
        gemm_bf16_kernel<2><<<dim3(4,8,8), 256, 0, stream>>>(volf_bf, linv_bf, nullptr, lvparts, nullptr,
                                                             512, 256, 1024, 2, 512*256);
        bf16* c3act2 = (bf16*)(base + 27332096);
        float* parts2 = (float*)(base + 27332096 + (size_t)1024*10368*2);
        for (int ch=0; ch<2; ++ch){
            int img0 = ch*1024;
            patchconv_kernel<<<1024, 256, 0, stream>>>(views, p2d, qtime, P_c1w, P_c1b,
                                                       w2cl, P_c2b, w3cl, P_c3b, c3act2, img0, flag);
            gemm128_kernel<<<dim3(4, 8, 8), 256, 0, stream>>>(c3act2, m1w_bf, parts2,
                                                              512, 10368, 162, 8, 1024*512);
            mlp1_fin_kernel<<<512, 256, 0, stream>>>(parts2, P_m1b, mlp1o_bf + (size_t)img0*512,
                                                     1024*512, 511, 1024*512);
        }
    }
    // m2: split-K=2 -> 256 blocks; partials summed inside terms
    gemm_bf16_kernel<2><<<dim3(4,32,2), 256, 0, stream>>>(mlp1o_bf, m2w_bf, nullptr, m2parts, nullptr,
                                                          2048, 256, 512, 4, 2048*256);
    terms_kernel<<<2048, 256, 0, stream>>>(p2d, visf, lvparts, P_linvb, m2parts, P_m2b,
                                           linpwT, P_linpb, lindwT, P_lindb,
                                           P_tq, P_tt, P_vtab, P_gw, P_gb,
                                           qtime, ttime, P_qc, P_camC, P_csc, P_dns, fusedb_bf);
    gemm_bf16_kernel<1><<<dim3(16,32,1), 256, 0, stream>>>(fusedb_bf, f1w_bf, P_f1b, nullptr, hbuf_bf,
                                                           2048, 1024, 256, 4, 0);
    gemm_bf16_kernel<2><<<dim3(4,32,4), 256, 0, stream>>>(hbuf_bf, f2w_bf, nullptr, f2parts, nullptr,
                                                          2048, 256, 1024, 4, 2048*256);
    fin2_kernel<<<512, 256, 0, stream>>>(f2parts, P_f2b, d_out, flag, 2048*256, 255, 2048*256);
    (void)in_sizes; (void)n_in; (void)out_size;
}

// Round 7
// 376.162 us; speedup vs baseline: 1.1066x; 1.1066x over previous
//
#include <hip/hip_runtime.h>
#include <hip/hip_bf16.h>

typedef __hip_bfloat16 bf16;
typedef __attribute__((ext_vector_type(8))) short short8;
typedef __attribute__((ext_vector_type(4))) float floatx4;

#define NC 4
#define BB 2
#define TS 16
#define CHN 3
#define HH 256
#define WW 256
#define KQ 256
#define EE 256
#define BKT 512          // B*K
#define HW 65536         // H*W
#define NSEG 25
#define CH1 32
#define CH1P 40
#define CH2 64
#define CH2P 72
#define PW 11            // plane width (11 cols)

// prep_kernel segment boundaries (flat blockIdx.x ranges)
#define PB_WCL   32      // [0,32)      convert small tensors -> fp32 pool
#define PB_W23   160     // [32,160)    conv2/3 weights -> channel-last bf16
#define PB_AUXW  416     // [160,416)   linv/f1/f2/m2 -> bf16
#define PB_PROJ  424     // [416,424)   projection (8 blocks)
#define PB_CUBE  936     // [424,936)   cube sampling + fused v2v conv3d (512 blocks)
#define PB_M1W   1448    // [936,1448)  m1w -> bf16 PERMUTED [pos][oc] (512 blocks)
#define PB_END   1452    // [1448,1452) lin_pos_w/lin_depth_w transpose (4 blocks)

__device__ __forceinline__ float tof(bf16 x){ return __bfloat162float(x); }
__device__ __forceinline__ bf16 tobf(float x){ return __float2bfloat16(x); }
// erf via Abramowitz-Stegun 7.1.26 (|eps| <= 1.5e-7, branch-free, native exp)
__device__ __forceinline__ float gelu_f(float x){
    float t = fabsf(x) * 0.70710678118654752f;
    float k = __builtin_amdgcn_rcpf(fmaf(0.3275911f, t, 1.f));
    float p = fmaf(fmaf(fmaf(fmaf(1.061405429f, k, -1.453152027f), k,
                   1.421413741f), k, -0.284496736f), k, 0.254829592f) * k;
    float e = __expf(-t*t);
    float er = fmaf(-p, e, 1.f);
    float s = copysignf(er, x);
    return 0.5f*x*(1.f + s);
}
__device__ __forceinline__ float ldx(const void* p, size_t i, int bf){
    return bf ? tof(((const bf16*)p)[i]) : ((const float*)p)[i];
}
__device__ __forceinline__ void gload_lds16(const void* g, void* l){
    __builtin_amdgcn_global_load_lds((const __attribute__((address_space(1))) void*)g,
                                     (__attribute__((address_space(3))) void*)l, 16, 0, 0);
}
__device__ __forceinline__ unsigned pack2(float a, float b){
    union{ bf16 h[2]; unsigned u; } pk; pk.h[0]=tobf(a); pk.h[1]=tobf(b); return pk.u;
}

struct CvtArgs { const void* src[NSEG]; int dstoff[NSEG]; int cnt[NSEG]; };

struct PrepArgs {
    const void *camF, *camR, *camC, *camP, *qc, *csc;
    const void *c2w, *c3w, *linv, *f1w, *f2w, *m2w, *m1w, *views;
    const void *v2vw, *v2vb;
    const void *linpw, *lindw;
    const int* qtime;
    bf16 *w2cl, *w3cl, *linv_bf, *f1w_bf, *f2w_bf, *m2w_bf, *m1w_bf;
    float *p2d, *visf;
    float *linpwT, *lindwT;
    bf16* volf;
    void* dout;
    int* flagp;
};

union PrepSm {
    struct { float vol[3][7][7][7]; float ws[648]; float bs[8]; } cube;  // 6,740 B
    bf16 lin[10368];                                                     // 20,736 B
};

// ---------------------------------------------------------------- fused prep
__global__ __launch_bounds__(256) void prep_kernel(CvtArgs ca, float* __restrict__ pool, PrepArgs a)
{
    int bid = blockIdx.x, tid = threadIdx.x;
    int bf = (((const unsigned short*)a.camF)[0] != 0) ? 1 : 0;
    __shared__ PrepSm sm;

    if (bid < PB_WCL){
        for (int s=0; s<NSEG; ++s){
            const void* src = ca.src[s];
            float* d = pool + ca.dstoff[s];
            int n = ca.cnt[s];
            for (int i = bid*256 + tid; i < n; i += PB_WCL*256) d[i] = ldx(src, i, bf);
        }
    } else if (bid < PB_W23){
        int i0 = (bid-PB_WCL)*256 + tid;
        const int stride = (PB_W23-PB_WCL)*256;
        for (int i=i0; i<64*32*9; i+=stride){
            int oc=i/(32*9), r=i%(32*9), ic=r/9, tap=r%9;
            a.w2cl[tap*(64*CH1) + oc*CH1 + ic] = tobf(ldx(a.c2w, i, bf));
        }
        for (int i=i0; i<128*64*9; i+=stride){
            int oc=i/(64*9), r=i%(64*9), ic=r/9, tap=r%9;
            a.w3cl[tap*(128*CH2) + oc*CH2 + ic] = tobf(ldx(a.c3w, i, bf));
        }
    } else if (bid < PB_AUXW){
        int sub = (bid-PB_W23)>>6;
        int i0 = ((bid-PB_W23)&63)*256 + tid;
        const int stride = 64*256;
        if (sub==0){
            for (int i=i0; i<256*1024; i+=stride){
                int r=i>>10, c=i&1023;
                a.linv_bf[i] = tobf(c<1000 ? ldx(a.linv, (size_t)r*1000+c, bf) : 0.f);
            }
        } else if (sub==1){
            for (int i=i0; i<1024*256; i+=stride) a.f1w_bf[i]=tobf(ldx(a.f1w,i,bf));
        } else if (sub==2){
            for (int i=i0; i<256*1024; i+=stride) a.f2w_bf[i]=tobf(ldx(a.f2w,i,bf));
        } else {
            for (int i=i0; i<256*512; i+=stride) a.m2w_bf[i]=tobf(ldx(a.m2w,i,bf));
        }
    } else if (bid < PB_PROJ){
        if (bid==PB_AUXW && tid==0) *a.flagp = bf;
        int idx = (bid-PB_AUXW)*256 + tid;
        if (idx < NC*BKT){
            int c = idx / BKT, bk = idx % BKT;
            float dx = ldx(a.qc,bk*3+0,bf) - ldx(a.camC,c*3+0,bf);
            float dy = ldx(a.qc,bk*3+1,bf) - ldx(a.camC,c*3+1,bf);
            float dz = ldx(a.qc,bk*3+2,bf) - ldx(a.camC,c*3+2,bf);
            float X0 = ldx(a.camR,c*9+0,bf)*dx + ldx(a.camR,c*9+1,bf)*dy + ldx(a.camR,c*9+2,bf)*dz;
            float X1 = ldx(a.camR,c*9+3,bf)*dx + ldx(a.camR,c*9+4,bf)*dy + ldx(a.camR,c*9+5,bf)*dz;
            float X2 = ldx(a.camR,c*9+6,bf)*dx + ldx(a.camR,c*9+7,bf)*dy + ldx(a.camR,c*9+8,bf)*dz;
            float z = fmaxf(X2, 1e-6f);
            float u = X0/z*ldx(a.camF,c*2+0,bf) + ldx(a.camP,c*2+0,bf);
            float v = X1/z*ldx(a.camF,c*2+1,bf) + ldx(a.camP,c*2+1,bf);
            a.p2d[idx*2+0] = u; a.p2d[idx*2+1] = v;
            bool vis = (X2 > 0.f) && (u >= 2.f) && (u <= (float)WW-2.f) && (v >= 2.f) && (v <= (float)HH-2.f);
            a.visf[idx] = vis ? 1.f : 0.f;
            float vv = vis ? 1.f : 0.f;
            size_t vidx = (size_t)BB*KQ*NC*EE + (size_t)bk*NC + c;
            if (bf) ((bf16*)a.dout)[vidx] = tobf(vv);
            else    ((float*)a.dout)[vidx] = vv;
        }
    } else if (bid < PB_CUBE){
        // cube sampling ((p,cam)-parallel, 4-lane shuffle reduce) + fused v2v conv3d
        int bk = bid - PB_PROJ;
        int c = tid & 3;
        int pg = tid >> 2;
        int b = bk >> 8;
        for (int i=tid; i<3*343; i+=256) ((float*)sm.cube.vol)[i]=0.f;
        for (int i=tid; i<648; i+=256) sm.cube.ws[i]=ldx(a.v2vw,i,bf);
        if (tid<8) sm.cube.bs[tid]=ldx(a.v2vb,tid,bf);
        __syncthreads();
        float cs2 = ldx(a.csc,0,bf) * 2.f;
        int t = a.qtime[bk];
        float qx0 = ldx(a.qc,bk*3+0,bf);
        float qy0 = ldx(a.qc,bk*3+1,bf);
        float qz0 = ldx(a.qc,bk*3+2,bf);
        float R0=ldx(a.camR,c*9+0,bf), R1=ldx(a.camR,c*9+1,bf), R2=ldx(a.camR,c*9+2,bf);
        float R3=ldx(a.camR,c*9+3,bf), R4=ldx(a.camR,c*9+4,bf), R5=ldx(a.camR,c*9+5,bf);
        float R6=ldx(a.camR,c*9+6,bf), R7=ldx(a.camR,c*9+7,bf), R8=ldx(a.camR,c*9+8,bf);
        float Cx=ldx(a.camC,c*3+0,bf), Cy=ldx(a.camC,c*3+1,bf), Cz=ldx(a.camC,c*3+2,bf);
        float Fx=ldx(a.camF,c*2+0,bf), Fy=ldx(a.camF,c*2+1,bf);
        float Px=ldx(a.camP,c*2+0,bf), Py=ldx(a.camP,c*2+1,bf);
        #pragma unroll
        for (int pass=0; pass<2; ++pass){
            int p = (pass<<6) + pg;
            bool act = p < 125;
            int i=p/25, j=(p/5)%5, kz=p%5;
            float a0=0.f,a1=0.f,a2=0.f,ms=0.f;
            if (act){
                float qx = qx0 + (float)(i-2)*cs2;
                float qy = qy0 + (float)(j-2)*cs2;
                float qz = qz0 + (float)(kz-2)*cs2;
                float dx=qx-Cx, dy=qy-Cy, dz=qz-Cz;
                float X0=R0*dx+R1*dy+R2*dz;
                float X1=R3*dx+R4*dy+R5*dz;
                float X2=R6*dx+R7*dy+R8*dz;
                float z = fmaxf(X2,1e-6f);
                float u = X0/z*Fx+Px, v = X1/z*Fy+Py;
                if (u>=0.f && u<=(float)WW && v>=0.f && v<=(float)HH){
                    ms = 1.f;
                    float x = u-0.5f, y = v-0.5f;
                    float xf = floorf(x), yf = floorf(y);
                    int ix=(int)xf, iy=(int)yf;
                    float wx=x-xf, wy=y-yf;
                    size_t basev = (size_t)((c*BB+b)*TS + t)*CHN*HW;
                    float wxs[2]={1.f-wx,wx}, wys[2]={1.f-wy,wy};
                    #pragma unroll
                    for (int ty=0;ty<2;++ty){
                        int yy=iy+ty; if (yy<0||yy>=HH) continue;
                        #pragma unroll
                        for (int tx=0;tx<2;++tx){
                            int xx=ix+tx; if (xx<0||xx>=WW) continue;
                            float wt=wys[ty]*wxs[tx];
                            size_t o = basev + (size_t)yy*WW+xx;
                            a0 += wt*ldx(a.views,o,bf);
                            a1 += wt*ldx(a.views,o+HW,bf);
                            a2 += wt*ldx(a.views,o+2*HW,bf);
                        }
                    }
                }
            }
            a0 += __shfl_xor(a0,1); a0 += __shfl_xor(a0,2);
            a1 += __shfl_xor(a1,1); a1 += __shfl_xor(a1,2);
            a2 += __shfl_xor(a2,1); a2 += __shfl_xor(a2,2);
            ms += __shfl_xor(ms,1); ms += __shfl_xor(ms,2);
            if (act && c==0){
                float cnt = fmaxf(ms,1.f);
                sm.cube.vol[0][kz+1][j+1][i+1]=a0/cnt;
                sm.cube.vol[1][kz+1][j+1][i+1]=a1/cnt;
                sm.cube.vol[2][kz+1][j+1][i+1]=a2/cnt;
            }
        }
        __syncthreads();
        if (tid >= 104 && tid < 128) a.volf[bk*1024 + 1000 + (tid-104)] = tobf(0.f);
        if (tid < 125){
            int w2=tid/25, h2=(tid/5)%5, d2=tid%5;
            for (int oc=0;oc<8;++oc){
                float acc = sm.cube.bs[oc];
                #pragma unroll
                for (int ic=0;ic<3;++ic)
                  #pragma unroll
                  for (int dz=0;dz<3;++dz)
                    #pragma unroll
                    for (int dy=0;dy<3;++dy)
                      #pragma unroll
                      for (int dxx=0;dxx<3;++dxx)
                        acc += sm.cube.vol[ic][d2+dz][h2+dy][w2+dxx] * sm.cube.ws[(((oc*3+ic)*3+dz)*3+dy)*3+dxx];
                a.volf[bk*1024 + oc*125 + tid] = tobf(gelu_f(acc));
            }
        }
    } else if (bid < PB_M1W){
        // m1w row -> bf16 with K-permutation [oc*81+pos] -> [pos*128+oc]
        int n = bid - PB_CUBE;
        const size_t off = (size_t)n*10368;
        if (bf){
            const bf16* s = (const bf16*)a.m1w + off;
            for (int i=tid;i<10368;i+=256) sm.lin[i]=s[i];
        } else {
            const float* s = (const float*)a.m1w + off;
            for (int i=tid;i<10368;i+=256) sm.lin[i]=tobf(s[i]);
        }
        __syncthreads();
        unsigned* d = (unsigned*)(a.m1w_bf + off);
        for (int j2=tid; j2<5184; j2+=256){
            int j = j2*2;
            int pos0=j>>7, oc0=j&127;
            int pos1=(j+1)>>7, oc1=(j+1)&127;
            d[j2] = pack2(tof(sm.lin[oc0*81+pos0]), tof(sm.lin[oc1*81+pos1]));
        }
    } else {
        // lin_pos_w [256][40] -> [40][256], lin_depth_w [256][20] -> [20][256]
        int i0 = (bid-PB_M1W)*256 + tid;
        for (int o=i0; o<10240; o+=1024){
            int j=o>>8, e=o&255;
            a.linpwT[o] = ldx(a.linpw, (size_t)e*40+j, bf);
        }
        for (int o=i0; o<5120; o+=1024){
            int j=o>>8, e=o&255;
            a.lindwT[o] = ldx(a.lindw, (size_t)e*20+j, bf);
        }
    }
}

// ---------------------------------------------------------------- patchconv shared-mem layout
// Lifetime overlay: {w1s,patch} (dead after conv1) unioned with a2cl (live from
// conv2). 32,012 -> 27,104 B => 6 blocks/CU (was 5). Costs one extra zero-phase.
struct __align__(16) PCShared {
    union __align__(16) {
        bf16 a2cl[11*PW*CH2P];                               // 17,424 B
        struct { float w1s[864]; float patch[3][11][11]; } c1; // 4,908 B
    } u;
    __align__(16) bf16 a1cl[11*PW*CH1P];                     // 9,680 B
};
struct __align__(16) LVShared {
    bf16 As[64][72];
    bf16 Bs[64][72];         // 18,432 B total
};
struct __align__(16) G128Shared {
    bf16 As[128][64];
    bf16 Bs[128][64];        // 32,768 B total
};

// fused patch sample + conv1 (VALU) + conv2/conv3 (MFMA, swapped operands:
// mfma(W,Act) -> D[oc][pos], lane holds 4 consecutive oc -> 8B packed writes).
// act_out layout: [img][pos*128+oc] (m1w permuted to match).
__device__ __forceinline__ void patchconv_body(
    PCShared& sm, int img,
    const void* __restrict__ views, const float* __restrict__ p2d,
    const int* __restrict__ qtime,
    const float* __restrict__ w1, const float* __restrict__ b1,
    const bf16* __restrict__ w2cl, const float* __restrict__ b2,
    const bf16* __restrict__ w3cl, const float* __restrict__ b3,
    bf16* __restrict__ act_out, const int* __restrict__ flagp)
{
    int c = img>>9, b = (img>>8)&1, k = img&255;
    int bk = b*KQ + k;
    int tid = threadIdx.x;
    int wave = tid>>6, lane = tid&63;

    // phase 0: zero a1cl + patch, load w1s
    {
        unsigned int* z1=(unsigned int*)sm.a1cl; int n1 = 11*PW*CH1P/2;
        for (int i=tid;i<n1;i+=256) z1[i]=0u;
    }
    for (int i=tid;i<3*11*11;i+=256) ((float*)sm.u.c1.patch)[i]=0.f;
    for (int i=tid;i<864;i+=256) sm.u.c1.w1s[i]=w1[i];
    __syncthreads();
    // phase 1: sampling, one thread per (position, channel)
    if (tid<243){
        int bf = *flagp;
        int ch = tid/81;
        int pp = tid - ch*81;
        float u=p2d[(c*BKT+bk)*2+0], v=p2d[(c*BKT+bk)*2+1];
        int t=qtime[bk];
        int r=pp/9,q=pp%9;
        float x=u+(float)(q-4), y=v+(float)(r-4);
        float xf=floorf(x), yf=floorf(y);
        int ix=(int)xf, iy=(int)yf;
        float wx=x-xf, wy=y-yf;
        size_t base = (size_t)((c*BB+b)*TS+t)*CHN*HW + (size_t)ch*HW;
        float acc=0.f;
        float wxs[2]={1.f-wx,wx}, wys[2]={1.f-wy,wy};
        #pragma unroll
        for (int ty=0;ty<2;++ty){
            int yy=iy+ty; if (yy<0||yy>=HH) continue;
            #pragma unroll
            for (int tx=0;tx<2;++tx){
                int xx=ix+tx; if (xx<0||xx>=WW) continue;
                acc += wys[ty]*wxs[tx]*ldx(views, base + (size_t)yy*WW+xx, bf);
            }
        }
        sm.u.c1.patch[ch][r+1][q+1]=acc;
    }
    __syncthreads();
    // phase 2: conv1 (reads patch/w1s, writes a1cl)
    for (int o=tid;o<81*32;o+=256){
        int oc=o&31, pp=o>>5;
        int r=pp/9, q=pp-9*r;
        float acc=b1[oc];
        #pragma unroll
        for (int ic=0;ic<3;++ic)
          #pragma unroll
          for (int dy2=0;dy2<3;++dy2)
            #pragma unroll
            for (int dx2=0;dx2<3;++dx2)
              acc += sm.u.c1.patch[ic][r+dy2][q+dx2]*sm.u.c1.w1s[((oc*3+ic)*3+dy2)*3+dx2];
        sm.a1cl[((r+1)*PW+(q+1))*CH1P + oc] = tobf(gelu_f(acc));
    }
    __syncthreads();
    // phase 3: zero a2cl (w1s/patch now dead)
    {
        unsigned int* z2=(unsigned int*)sm.u.a2cl; int n2 = 11*PW*CH2P/2;
        for (int i=tid;i<n2;i+=256) z2[i]=0u;
    }
    __syncthreads();
    int mrow = lane&15;
    int kgrp = lane>>4;
    int koff = kgrp<<3;
    // phase 4: conv2 (reads a1cl, writes a2cl interior) D[oc][pos]
    {
        int baseoff[6];
        #pragma unroll
        for (int m=0;m<6;++m){
            int pos = m*16 + mrow; if (pos>80) pos=80;
            int r=pos/9, q=pos-9*r;
            baseoff[m] = (r*PW+q)*CH1P + koff;
        }
        floatx4 acc2[6];
        #pragma unroll
        for (int m=0;m<6;++m) acc2[m]=(floatx4){0.f,0.f,0.f,0.f};
        int n0 = wave<<4;
        #pragma unroll
        for (int tap=0; tap<9; ++tap){
            int dy=tap/3, dx=tap-3*dy;
            short8 wfrag = *(const short8*)(w2cl + ((size_t)tap*64 + n0 + mrow)*CH1 + koff);
            int toff = (dy*PW+dx)*CH1P;
            #pragma unroll
            for (int m=0;m<6;++m){
                short8 afrag = *(const short8*)&sm.a1cl[baseoff[m]+toff];
                acc2[m] = __builtin_amdgcn_mfma_f32_16x16x32_bf16(wfrag, afrag, acc2[m], 0,0,0);
            }
        }
        int ocb = n0 + (kgrp<<2);
        float bb0=b2[ocb], bb1=b2[ocb+1], bb2=b2[ocb+2], bb3=b2[ocb+3];
        #pragma unroll
        for (int m=0;m<6;++m){
            int pos = m*16 + mrow;
            if (pos<=80){
                int r=pos/9,q=pos-9*r;
                uint2 pk;
                pk.x = pack2(gelu_f(acc2[m][0]+bb0), gelu_f(acc2[m][1]+bb1));
                pk.y = pack2(gelu_f(acc2[m][2]+bb2), gelu_f(acc2[m][3]+bb3));
                *(uint2*)&sm.u.a2cl[((r+1)*PW+(q+1))*CH2P + ocb] = pk;
            }
        }
    }
    __syncthreads();
    // phase 5: conv3 D[oc][pos]
    {
        int baseoff[6];
        #pragma unroll
        for (int m=0;m<6;++m){
            int pos = m*16 + mrow; if (pos>80) pos=80;
            int r=pos/9, q=pos-9*r;
            baseoff[m] = (r*PW+q)*CH2P;
        }
        floatx4 acc3[2][6];
        #pragma unroll
        for (int nt=0;nt<2;++nt)
          #pragma unroll
          for (int m=0;m<6;++m) acc3[nt][m]=(floatx4){0.f,0.f,0.f,0.f};
        int n0 = wave<<5;
        #pragma unroll
        for (int tap=0; tap<9; ++tap){
            int dy=tap/3, dx=tap-3*dy;
            int toff = (dy*PW+dx)*CH2P;
            #pragma unroll
            for (int ks=0;ks<2;++ks){
                int kof2 = (ks<<5) + koff;
                short8 w0 = *(const short8*)(w3cl + ((size_t)tap*128 + n0      + mrow)*CH2 + kof2);
                short8 w1f= *(const short8*)(w3cl + ((size_t)tap*128 + n0 + 16 + mrow)*CH2 + kof2);
                #pragma unroll
                for (int m=0;m<6;++m){
                    short8 af = *(const short8*)&sm.u.a2cl[baseoff[m]+toff+kof2];
                    acc3[0][m] = __builtin_amdgcn_mfma_f32_16x16x32_bf16(w0,  af, acc3[0][m], 0,0,0);
                    acc3[1][m] = __builtin_amdgcn_mfma_f32_16x16x32_bf16(w1f, af, acc3[1][m], 0,0,0);
                }
            }
        }
        bf16* outp = act_out + (size_t)img*10368;
        #pragma unroll
        for (int nt=0;nt<2;++nt){
            int ocb = n0 + (nt<<4) + (kgrp<<2);
            float bb0=b3[ocb], bb1=b3[ocb+1], bb2=b3[ocb+2], bb3=b3[ocb+3];
            #pragma unroll
            for (int m=0;m<6;++m){
                int pos = m*16 + mrow;
                if (pos<=80){
                    uint2 pk;
                    pk.x = pack2(gelu_f(acc3[nt][m][0]+bb0), gelu_f(acc3[nt][m][1]+bb1));
                    pk.y = pack2(gelu_f(acc3[nt][m][2]+bb2), gelu_f(acc3[nt][m][3]+bb3));
                    *(uint2*)&outp[pos*128 + ocb] = pk;
                }
            }
        }
    }
}

// linvol 64x64 GEMM body (single-buffered), split-K z-slice -> private partials
__device__ __forceinline__ void linvol_body(
    LVShared& sm, int r, const bf16* __restrict__ A, const bf16* __restrict__ W,
    float* __restrict__ lvparts)
{
    int tid = threadIdx.x;
    int wave = tid>>6, lane = tid&63;
    int z = r>>5, rem = r&31, by = rem>>2, bx = rem&3;
    int m0 = by<<6, n0 = bx<<6;
    int kt0 = z*2;
    int lr = tid>>3, lc = (tid&7)<<3;
    floatx4 acc[4];
    #pragma unroll
    for (int j=0;j<4;++j) acc[j]=(floatx4){0.f,0.f,0.f,0.f};
    int arow = (wave<<4) + (lane&15);
    int koff = (lane>>4)<<3;
    int nrow = lane&15;
    for (int it=0; it<2; ++it){
        int ko = (kt0+it)<<6;
        *(uint4*)&sm.As[lr][lc]    = *(const uint4*)(A + (size_t)(m0+lr)*1024    + ko + lc);
        *(uint4*)&sm.As[lr+32][lc] = *(const uint4*)(A + (size_t)(m0+lr+32)*1024 + ko + lc);
        *(uint4*)&sm.Bs[lr][lc]    = *(const uint4*)(W + (size_t)(n0+lr)*1024    + ko + lc);
        *(uint4*)&sm.Bs[lr+32][lc] = *(const uint4*)(W + (size_t)(n0+lr+32)*1024 + ko + lc);
        __syncthreads();
        #pragma unroll
        for (int kk=0; kk<64; kk+=32){
            short8 af = *(const short8*)&sm.As[arow][kk+koff];
            #pragma unroll
            for (int j=0;j<4;++j){
                short8 wf = *(const short8*)&sm.Bs[(j<<4)+nrow][kk+koff];
                acc[j] = __builtin_amdgcn_mfma_f32_16x16x32_bf16(af, wf, acc[j], 0,0,0);
            }
        }
        __syncthreads();
    }
    float* out = lvparts + (size_t)z * (512*256);
    int crow = (wave<<4) + ((lane>>4)<<2);
    int ccol = lane&15;
    #pragma unroll
    for (int j=0;j<4;++j){
        int n = n0 + (j<<4) + ccol;
        #pragma unroll
        for (int rr=0;rr<4;++rr)
            out[(size_t)(m0+crow+rr)*256 + n] = acc[j][rr];
    }
}

// fused launch: blocks [0,npc) = patchconv, [npc, npc+256) = linvol split-K GEMM
__global__ __launch_bounds__(256) void patchlin_kernel(
    const void* __restrict__ views, const float* __restrict__ p2d,
    const int* __restrict__ qtime,
    const float* __restrict__ w1, const float* __restrict__ b1,
    const bf16* __restrict__ w2cl, const float* __restrict__ b2,
    const bf16* __restrict__ w3cl, const float* __restrict__ b3,
    bf16* __restrict__ act_out, int img0, int npc, const int* __restrict__ flagp,
    const bf16* __restrict__ volf, const bf16* __restrict__ linvw,
    float* __restrict__ lvparts)
{
    __shared__ union { PCShared pc; LVShared lv; } sm;
    int bid = blockIdx.x;
    if (bid < npc){
        patchconv_body(sm.pc, img0+bid, views, p2d, qtime, w1, b1, w2cl, b2, w3cl, b3,
                       act_out, flagp);
    } else {
        linvol_body(sm.lv, bid-npc, volf, linvw, lvparts);
    }
}

// standalone patchconv (fallback)
__global__ __launch_bounds__(256) void patchconv_kernel(
    const void* __restrict__ views, const float* __restrict__ p2d,
    const int* __restrict__ qtime,
    const float* __restrict__ w1, const float* __restrict__ b1,
    const bf16* __restrict__ w2cl, const float* __restrict__ b2,
    const bf16* __restrict__ w3cl, const float* __restrict__ b3,
    bf16* __restrict__ act_out, int img0, const int* __restrict__ flagp)
{
    __shared__ PCShared sm;
    patchconv_body(sm, img0+blockIdx.x, views, p2d, qtime, w1, b1, w2cl, b2, w3cl, b3,
                   act_out, flagp);
}

// ---------------------------------------------------------------- generic MFMA bf16 GEMM, double-buffered LDS + reg prefetch
// OUT=1: bf16 = gelu(acc+bias); OUT=2: fp32 store (z-slice -> Cf + z*pstride)
template<int OUT>
__global__ __launch_bounds__(256) void gemm_bf16_kernel(
    const bf16* __restrict__ A, const bf16* __restrict__ W, const float* __restrict__ bias,
    float* __restrict__ Cf, void* __restrict__ Cb, int M, int N, int K, int iters,
    int pstride)
{
    __shared__ bf16 As[2][64][72];
    __shared__ bf16 Bs[2][64][72];
    int tid = threadIdx.x;
    int wave = tid>>6, lane = tid&63;
    int m0 = blockIdx.y<<6, n0 = blockIdx.x<<6;
    int kt0 = blockIdx.z*iters;
    int lr = tid>>3;
    int lc = (tid&7)<<3;
    const bf16* Ap0 = A + (size_t)(m0+lr)*K    + (kt0<<6) + lc;
    const bf16* Ap1 = A + (size_t)(m0+lr+32)*K + (kt0<<6) + lc;
    const bf16* Wp0 = W + (size_t)(n0+lr)*K    + (kt0<<6) + lc;
    const bf16* Wp1 = W + (size_t)(n0+lr+32)*K + (kt0<<6) + lc;
    uint4 ra0 = *(const uint4*)Ap0;
    uint4 ra1 = *(const uint4*)Ap1;
    uint4 rb0 = *(const uint4*)Wp0;
    uint4 rb1 = *(const uint4*)Wp1;
    floatx4 acc[4];
    #pragma unroll
    for (int j=0;j<4;++j) acc[j] = (floatx4){0.f,0.f,0.f,0.f};
    int arow = (wave<<4) + (lane&15);
    int koff = (lane>>4)<<3;
    int nrow = lane&15;
    *(uint4*)&As[0][lr][lc]    = ra0;
    *(uint4*)&As[0][lr+32][lc] = ra1;
    *(uint4*)&Bs[0][lr][lc]    = rb0;
    *(uint4*)&Bs[0][lr+32][lc] = rb1;
    __syncthreads();
    for (int it=0; it<iters; ++it){
        int cur = it&1;
        if (it+1<iters){
            int off = (it+1)<<6;
            ra0 = *(const uint4*)(Ap0+off);
            ra1 = *(const uint4*)(Ap1+off);
            rb0 = *(const uint4*)(Wp0+off);
            rb1 = *(const uint4*)(Wp1+off);
        }
        #pragma unroll
        for (int kk=0; kk<64; kk+=32){
            short8 af = *(const short8*)&As[cur][arow][kk+koff];
            #pragma unroll
            for (int j=0;j<4;++j){
                short8 bfr = *(const short8*)&Bs[cur][(j<<4)+nrow][kk+koff];
                acc[j] = __builtin_amdgcn_mfma_f32_16x16x32_bf16(af, bfr, acc[j], 0, 0, 0);
            }
        }
        if (it+1<iters){
            __syncthreads();
            int nxt = cur^1;
            *(uint4*)&As[nxt][lr][lc]    = ra0;
            *(uint4*)&As[nxt][lr+32][lc] = ra1;
            *(uint4*)&Bs[nxt][lr][lc]    = rb0;
            *(uint4*)&Bs[nxt][lr+32][lc] = rb1;
            __syncthreads();
        }
    }
    int crow = (wave<<4) + ((lane>>4)<<2);
    int ccol = lane&15;
    #pragma unroll
    for (int j=0;j<4;++j){
        int n = n0 + (j<<4) + ccol;
        if (OUT==1){
            float bb = bias[n];
            #pragma unroll
            for (int r=0;r<4;++r)
                ((bf16*)Cb)[(size_t)(m0+crow+r)*N + n] = tobf(gelu_f(acc[j][r] + bb));
        } else {
            float* out = Cf + (size_t)blockIdx.z * pstride;
            #pragma unroll
            for (int r=0;r<4;++r)
                out[(size_t)(m0+crow+r)*N + n] = acc[j][r];
        }
    }
}

// ---------------------------------------------------------------- m97-style 128x128-tile GEMM for mlp1 (K=10368)
__global__ __launch_bounds__(256) void gemm128_kernel(
    const bf16* __restrict__ A, const bf16* __restrict__ W,
    float* __restrict__ Cf, int N, int K, int kiters_total, int zdiv, int pstride)
{
    __shared__ G128Shared s;
    int tid = threadIdx.x;
    int wave = tid>>6, lane = tid&63;
    int m0 = blockIdx.y<<7, n0 = blockIdx.x<<7;
    int it0 = (int)(((long)blockIdx.z     * kiters_total) / zdiv);
    int it1 = (int)(((long)(blockIdx.z+1) * kiters_total) / zdiv);
    float* out = Cf + (size_t)blockIdx.z * pstride;
    int srow = (wave<<5) + (lane>>3);
    int scol = (lane&7)<<3;
    const bf16* Ap = A + (size_t)(m0+srow)*K + ((size_t)it0<<6) + scol;
    const bf16* Bp = W + (size_t)(n0+srow)*K + ((size_t)it0<<6) + scol;
    bf16* AsW = &s.As[wave<<5][0];
    bf16* BsW = &s.Bs[wave<<5][0];
    floatx4 acc[4][4];
    #pragma unroll
    for (int i=0;i<4;++i)
      #pragma unroll
      for (int j=0;j<4;++j) acc[i][j] = (floatx4){0.f,0.f,0.f,0.f};
    int wm = (wave>>1)<<6, wn = (wave&1)<<6;
    int frow = lane&15, koff = (lane>>4)<<3;
    for (int it=it0; it<it1; ++it){
        size_t off = (size_t)(it-it0)<<6;
        #pragma unroll
        for (int j=0;j<4;++j){
            gload_lds16(Ap + (size_t)(j<<3)*K + off, AsW + (j<<3)*64);
            gload_lds16(Bp + (size_t)(j<<3)*K + off, BsW + (j<<3)*64);
        }
        __syncthreads();
        #pragma unroll
        for (int kk=0;kk<64;kk+=32){
            short8 af[4], bfv[4];
            #pragma unroll
            for (int i=0;i<4;++i) af[i]  = *(const short8*)&s.As[wm + (i<<4) + frow][kk+koff];
            #pragma unroll
            for (int j=0;j<4;++j) bfv[j] = *(const short8*)&s.Bs[wn + (j<<4) + frow][kk+koff];
            #pragma unroll
            for (int i=0;i<4;++i)
              #pragma unroll
              for (int j=0;j<4;++j)
                acc[i][j] = __builtin_amdgcn_mfma_f32_16x16x32_bf16(af[i], bfv[j], acc[i][j], 0,0,0);
        }
        __syncthreads();
    }
    int crow = (lane>>4)<<2;
    int ccol = lane&15;
    #pragma unroll
    for (int i=0;i<4;++i){
        int mrow = m0 + wm + (i<<4) + crow;
        #pragma unroll
        for (int j=0;j<4;++j){
            int n = n0 + wn + (j<<4) + ccol;
            #pragma unroll
            for (int r=0;r<4;++r)
                out[(size_t)(mrow+r)*N + n] = acc[i][j][r];
        }
    }
}

// ---------------------------------------------------------------- mlp1 finalize: sum split-K partials + bias, gelu -> bf16
__global__ __launch_bounds__(256) void mlp1_fin_kernel(const float* __restrict__ P,
                                                       const float* __restrict__ bias,
                                                       bf16* __restrict__ Cb, int total, int Nmask,
                                                       int pstride){
    for (int i = blockIdx.x*256 + threadIdx.x; i < total; i += gridDim.x*256){
        float s = bias[i & Nmask];
        #pragma unroll
        for (int p=0;p<8;++p) s += P[(size_t)p*pstride + i];
        Cb[i] = tobf(gelu_f(s));
    }
}

// ---------------------------------------------------------------- fus2 finalize: sum 4 partials + bias -> d_out (dual dtype)
__global__ __launch_bounds__(256) void fin2_kernel(const float* __restrict__ P,
                                                   const float* __restrict__ bias,
                                                   void* __restrict__ out, const int* __restrict__ flagp,
                                                   int total, int mask, int pstride){
    int bf = *flagp;
    for (int i = blockIdx.x*256 + threadIdx.x; i < total; i += gridDim.x*256){
        float s = bias[i & mask];
        #pragma unroll
        for (int p=0;p<4;++p) s += P[(size_t)p*pstride + i];
        if (bf) ((bf16*)out)[i] = tobf(s);
        else    ((float*)out)[i] = s;
    }
}

// ---------------------------------------------------------------- terms + gates + fuse
__global__ __launch_bounds__(256) void terms_kernel(
    const float* __restrict__ p2d, const float* __restrict__ visf,
    const float* __restrict__ lvp, const float* __restrict__ linv_b,
    const float* __restrict__ m2p, const float* __restrict__ m2_b,
    const float* __restrict__ linpwT, const float* __restrict__ lin_pos_b,
    const float* __restrict__ lindwT, const float* __restrict__ lin_depth_b,
    const float* __restrict__ tq_emb, const float* __restrict__ tt_emb,
    const float* __restrict__ vis_tab,
    const float* __restrict__ gate_w, const float* __restrict__ gate_b,
    const int* __restrict__ qtime, const int* __restrict__ ttime,
    const float* __restrict__ qc, const float* __restrict__ camC,
    const float* __restrict__ csc, const float* __restrict__ dns,
    bf16* __restrict__ fused)
{
    int row = blockIdx.x;
    int c = row & 3; int bk = row >> 2;
    int tid = threadIdx.x;
    __shared__ float feats[40];
    __shared__ float dfeat[20];
    __shared__ float terms[7][256];
    __shared__ float wred[4][7];
    __shared__ float gates_s[7];
    float u = p2d[(c*BKT+bk)*2+0], v = p2d[(c*BKT+bk)*2+1];
    if (tid < 40){
        int j = tid/20; int rem = tid%20;
        float xval = (j==0) ? u*(1.f/(float)WW) : v*(1.f/(float)HH);
        int fi = rem % 10; bool iscos = (rem >= 10);
        float arg = xval * (float)(1<<fi) * 3.14159265358979323846f;
        feats[tid] = iscos ? cosf(arg) : sinf(arg);
    } else if (tid < 60){
        int rem = tid-40;
        float dx = qc[bk*3+0]-camC[c*3+0];
        float dy = qc[bk*3+1]-camC[c*3+1];
        float dz = qc[bk*3+2]-camC[c*3+2];
        float dep = sqrtf(dx*dx+dy*dy+dz*dz) / (csc[0] * dns[0]);
        int fi = rem % 10; bool iscos = (rem >= 10);
        float arg = dep * (float)(1<<fi) * 3.14159265358979323846f;
        dfeat[rem] = iscos ? cosf(arg) : sinf(arg);
    }
    __syncthreads();
    int e = tid;
    float pos = lin_pos_b[e];
    #pragma unroll
    for (int j2=0;j2<40;++j2) pos += feats[j2]*linpwT[j2*256+e];
    float dep = lin_depth_b[e];
    #pragma unroll
    for (int j2=0;j2<20;++j2) dep += dfeat[j2]*lindwT[j2*256+e];
    float vol = linv_b[e];
    #pragma unroll
    for (int p=0;p<8;++p) vol += lvp[(size_t)p*(512*256) + bk*256+e];
    int img = (c*BB + (bk>>8))*KQ + (bk&255);
    float pat = m2_b[e] + m2p[(size_t)img*256+e] + m2p[(size_t)(2048*256) + (size_t)img*256+e];
    int tq = qtime[bk], tt2 = ttime[bk];
    float qtv = tq_emb[tq*256+e];
    float ttv = tt_emb[tt2*256+e];
    int vb = (visf[c*BKT+bk] > 0.5f) ? 1 : 0;
    float viv = vis_tab[vb*256+e];
    terms[0][e]=pos; terms[1][e]=vol; terms[2][e]=pat; terms[3][e]=qtv;
    terms[4][e]=ttv; terms[5][e]=viv; terms[6][e]=dep;
    __syncthreads();
    float pg[7];
    #pragma unroll
    for (int g=0;g<7;++g) pg[g]=0.f;
    for (int j2=tid; j2<1792; j2+=256){
        float cv = ((const float*)terms)[j2];
        #pragma unroll
        for (int g=0;g<7;++g) pg[g] += cv * gate_w[g*1792 + j2];
    }
    #pragma unroll
    for (int g=0;g<7;++g){
        #pragma unroll
        for (int off=32; off>0; off>>=1) pg[g] += __shfl_down(pg[g], off, 64);
    }
    int wave = tid >> 6, lane = tid & 63;
    if (lane==0){
        #pragma unroll
        for (int g=0;g<7;++g) wred[wave][g]=pg[g];
    }
    __syncthreads();
    if (tid < 7){
        float s = wred[0][tid]+wred[1][tid]+wred[2][tid]+wred[3][tid] + gate_b[tid];
        gates_s[tid] = 1.f/(1.f+expf(-s));
    }
    __syncthreads();
    float fv = 0.f;
    #pragma unroll
    for (int g=0;g<7;++g) fv += gates_s[g]*terms[g][e];
    fused[(size_t)row*256 + e] = tobf(fv);
}

// ---------------------------------------------------------------- launch
extern "C" void kernel_launch(void* const* d_in, const int* in_sizes, int n_in,
                              void* d_out, int out_size, void* d_ws, size_t ws_size,
                              hipStream_t stream) {
    const void* views  = d_in[0];
    const int*  qtime  = (const int*)d_in[6];
    const int*  ttime  = (const int*)d_in[7];

    char* base = (char*)d_ws;
    int*   flag = (int*)base;                       // 256 B
    float* pool = (float*)(base + 256);

    CvtArgs ca; int poff = 0; int ns = 0;
    auto add = [&](const void* p, int n)->float* {
        ca.src[ns]=p; ca.dstoff[ns]=poff; ca.cnt[ns]=n;
        float* r = pool+poff; poff += n; ns++; return r;
    };
    float* P_camR = add(d_in[1],36);
    float* P_camC = add(d_in[2],12);
    float* P_camF = add(d_in[3],8);
    float* P_camP = add(d_in[4],8);
    float* P_qc   = add(d_in[5],1536);
    float* P_csc  = add(d_in[8],1);
    float* P_dns  = add(d_in[30],1);
    float* P_linvb= add(d_in[12],256);
    float* P_linpw= add(d_in[13],10240);
    float* P_linpb= add(d_in[14],256);
    float* P_lindw= add(d_in[15],5120);
    float* P_lindb= add(d_in[16],256);
    float* P_c1w  = add(d_in[17],864);
    float* P_c1b  = add(d_in[18],32);
    float* P_c2b  = add(d_in[20],64);
    float* P_c3b  = add(d_in[22],128);
    float* P_m1b  = add(d_in[24],512);
    float* P_m2b  = add(d_in[26],256);
    float* P_tq   = add(d_in[27],4096);
    float* P_tt   = add(d_in[28],4096);
    float* P_vtab = add(d_in[29],512);
    float* P_gw   = add(d_in[31],12544);
    float* P_gb   = add(d_in[32],7);
    float* P_f1b  = add(d_in[34],1024);
    float* P_f2b  = add(d_in[36],256);

    bf16* m1w_bf = (bf16*)(base + 4185600);          // 10,616,832 B
    bf16* w2cl   = (bf16*)(base + 14802432);         // 36,864 B
    bf16* w3cl   = (bf16*)(base + 14839296);         // 147,456 B
    bf16* linv_bf= (bf16*)(base + 14986752);         // 524,288 B
    bf16* f1w_bf = (bf16*)(base + 15511040);         // 524,288 B
    bf16* f2w_bf = (bf16*)(base + 16035328);         // 524,288 B
    bf16* m2w_bf = (bf16*)(base + 16559616);         // 262,144 B
    float* p2d   = (float*)(base + 16821760);        // 16,384 B
    float* visf  = (float*)(base + 16838144);        // 8,192 B
    bf16*  volf_bf = (bf16*)(base + 16846336);       // 1,048,576 B
    float* lvparts = (float*)(base + 17894912);      // 8 x 512x256 fp32 = 4,194,304 B
    float* linpwT  = (float*)(base + 22089216);      // 40,960 B
    float* lindwT  = (float*)(base + 22130176);      // 20,480 B
    bf16*  mlp1o_bf = (bf16*)(base + 24186368);      // 2,097,152 B
    bf16*  fusedb_bf= (bf16*)(base + 26283520);      // 1,048,576 B
    // region [27,332,096 ...): overlapping transients with disjoint lifetimes
    int NCH = (ws_size >= 103353856ull) ? 1 : 2;
    int MCH = 2048 / NCH;
    bf16*  c3act    = (bf16*)(base + 27332096);      // MCH*10368*2 B (dead after gemm128)
    bf16*  hbuf_bf  = (bf16*)(base + 27332096);      // 4 MB, written at fus1 (c3act dead)
    float* m2parts  = (float*)(base + 31526400);     // 2 x 2048x256 fp32 = 4 MB
    float* f2parts  = (float*)(base + 35720704);     // 4 x 2048x256 fp32 = 8 MB
    float* parts    = (float*)(base + 27332096 + (size_t)MCH*10368*2); // 8 x MCH*512 fp32

    PrepArgs pa;
    pa.camF=d_in[3]; pa.camR=d_in[1]; pa.camC=d_in[2]; pa.camP=d_in[4];
    pa.qc=d_in[5]; pa.csc=d_in[8];
    pa.c2w=d_in[19]; pa.c3w=d_in[21];
    pa.linv=d_in[11]; pa.f1w=d_in[33]; pa.f2w=d_in[35]; pa.m2w=d_in[25];
    pa.m1w=d_in[23]; pa.views=views;
    pa.v2vw=d_in[9]; pa.v2vb=d_in[10];
    pa.linpw=d_in[13]; pa.lindw=d_in[15];
    pa.qtime=qtime;
    pa.w2cl=w2cl; pa.w3cl=w3cl; pa.linv_bf=linv_bf; pa.f1w_bf=f1w_bf;
    pa.f2w_bf=f2w_bf; pa.m2w_bf=m2w_bf; pa.m1w_bf=m1w_bf;
    pa.p2d=p2d; pa.visf=visf; pa.volf=volf_bf;
    pa.linpwT=linpwT; pa.lindwT=lindwT;
    pa.dout=d_out; pa.flagp=flag;

    // one wide launch: all input-side prep (cvt/proj/cube+conv3d/m1w-permute/transpose)
    prep_kernel<<<PB_END, 256, 0, stream>>>(ca, pool, pa);

    if (NCH == 1){
        // patchconv (2048) + linvol split-K GEMM (256) in ONE launch
        patchlin_kernel<<<2048+256, 256, 0, stream>>>(views, p2d, qtime, P_c1w, P_c1b,
                                                      w2cl, P_c2b, w3cl, P_c3b, c3act, 0, 2048, flag,
                                                      volf_bf, linv_bf, lvparts);
        gemm128_kernel<<<dim3(4, 16, 8), 256, 0, stream>>>(c3act, m1w_bf, parts,
                                                           512, 10368, 162, 8, 2048*512);
        mlp1_fin_kernel<<<512, 256, 0, stream>>>(parts, P_m1b, mlp1o_bf, 2048*512, 511, 2048*512);
    } else {
        gemm_bf16_kernel<2><<<dim3(4,8,8), 256, 0, stream>>>(volf_bf, linv_bf, nullptr, lvparts, nullptr,
                                                             512, 256, 1024, 2, 512*256);
        for (int ch=0; ch<NCH; ++ch){
            int img0 = ch*MCH;
            patchconv_kernel<<<MCH, 256, 0, stream>>>(views, p2d, qtime, P_c1w, P_c1b,
                                                      w2cl, P_c2b, w3cl, P_c3b, c3act, img0, flag);
            gemm128_kernel<<<dim3(4, MCH/128, 8), 256, 0, stream>>>(c3act, m1w_bf, parts,
                                                                    512, 10368, 162, 8, MCH*512);
            mlp1_fin_kernel<<<512, 256, 0, stream>>>(parts, P_m1b, mlp1o_bf + (size_t)img0*512,
                                                     MCH*512, 511, MCH*512);
        }
    }
    // m2: split-K=2 -> 256 blocks; partials summed inside terms
    gemm_bf16_kernel<2><<<dim3(4,32,2), 256, 0, stream>>>(mlp1o_bf, m2w_bf, nullptr, m2parts, nullptr,
                                                          2048, 256, 512, 4, 2048*256);
    terms_kernel<<<2048, 256, 0, stream>>>(p2d, visf, lvparts, P_linvb, m2parts, P_m2b,
                                           linpwT, P_linpb, lindwT, P_lindb,
                                           P_tq, P_tt, P_vtab, P_gw, P_gb,
                                           qtime, ttime, P_qc, P_camC, P_csc, P_dns, fusedb_bf);
    gemm_bf16_kernel<1><<<dim3(16,32,1), 256, 0, stream>>>(fusedb_bf, f1w_bf, P_f1b, nullptr, hbuf_bf,
                                                           2048, 1024, 256, 4, 0);
    gemm_bf16_kernel<2><<<dim3(4,32,4), 256, 0, stream>>>(hbuf_bf, f2w_bf, nullptr, f2parts, nullptr,
                                                          2048, 256, 1024, 4, 2048*256);
    fin2_kernel<<<512, 256, 0, stream>>>(f2parts, P_f2b, d_out, flag, 2048*256, 255, 2048*256);
    (void)in_sizes; (void)n_in; (void)out_size;
}